// Round 1
// baseline (513.372 us; speedup 1.0000x reference)
//
#include <hip/hip_runtime.h>
#include <math.h>

#define THREADS 256

__global__ void zero_kernel(int* __restrict__ p, int n) {
  int i = blockIdx.x * blockDim.x + threadIdx.x;
  if (i < n) p[i] = 0;
}

__global__ void hist_kernel(const int* __restrict__ dst, int* __restrict__ cnt, int e) {
  int i = blockIdx.x * blockDim.x + threadIdx.x;
  if (i < e) atomicAdd(&cnt[dst[i]], 1);
}

// Block-local exclusive scan: each block scans 1024 elements (256 thr x 4).
__global__ void scan_part_kernel(const int* __restrict__ cnt, int* __restrict__ off,
                                 int* __restrict__ bsum, int n) {
  __shared__ int s[256];
  int t = threadIdx.x;
  int base = blockIdx.x * 1024;
  int idx = base + t * 4;
  int v0 = (idx + 0 < n) ? cnt[idx + 0] : 0;
  int v1 = (idx + 1 < n) ? cnt[idx + 1] : 0;
  int v2 = (idx + 2 < n) ? cnt[idx + 2] : 0;
  int v3 = (idx + 3 < n) ? cnt[idx + 3] : 0;
  int tsum = v0 + v1 + v2 + v3;
  s[t] = tsum;
  __syncthreads();
  for (int ofs = 1; ofs < 256; ofs <<= 1) {
    int add = (t >= ofs) ? s[t - ofs] : 0;
    __syncthreads();
    s[t] += add;
    __syncthreads();
  }
  int ex = s[t] - tsum;  // exclusive prefix of this thread within block
  if (idx + 0 < n) off[idx + 0] = ex;
  if (idx + 1 < n) off[idx + 1] = ex + v0;
  if (idx + 2 < n) off[idx + 2] = ex + v0 + v1;
  if (idx + 3 < n) off[idx + 3] = ex + v0 + v1 + v2;
  if (t == 255) bsum[blockIdx.x] = s[255];
}

__global__ void scan_blocks_kernel(int* __restrict__ bsum, int nb) {
  if (threadIdx.x == 0 && blockIdx.x == 0) {
    int run = 0;
    for (int b = 0; b < nb; ++b) { int t = bsum[b]; bsum[b] = run; run += t; }
  }
}

// Add block offsets, init cursors, compute dinv = rsqrt(deg) (deg = cnt + self-loop).
__global__ void scan_add_kernel(int* __restrict__ off, const int* __restrict__ bsum,
                                const int* __restrict__ cnt, int* __restrict__ cur,
                                float* __restrict__ dinv, int n, int e) {
  int i = blockIdx.x * blockDim.x + threadIdx.x;
  if (i < n) {
    int o = off[i] + bsum[i >> 10];
    off[i] = o;
    cur[i] = o;
    dinv[i] = rsqrtf((float)(cnt[i] + 1));
  }
  if (i == 0) off[n] = e;
}

__global__ void fill_kernel(const int* __restrict__ src, const int* __restrict__ dst,
                            int* __restrict__ cur, int* __restrict__ csr, int e) {
  int i = blockIdx.x * blockDim.x + threadIdx.x;
  if (i < e) {
    int d = dst[i];
    int pos = atomicAdd(&cur[d], 1);
    csr[pos] = src[i];
  }
}

// h1 = x @ W1   (x: [n,128], W1: [128,64] row-major)
__global__ __launch_bounds__(256) void gemm1_kernel(const float* __restrict__ x,
    const float* __restrict__ W1, float* __restrict__ h1, int n) {
  __shared__ float Ws[128 * 64];
  __shared__ float xs[4 * 128];
  for (int i = threadIdx.x; i < 128 * 64; i += 256) Ws[i] = W1[i];
  int ntiles = (n + 3) >> 2;
  int r = threadIdx.x >> 6;   // wave id = row within tile
  int c = threadIdx.x & 63;   // lane = output column
  for (int tile = blockIdx.x; tile < ntiles; tile += gridDim.x) {
    int row0 = tile * 4;
    __syncthreads();  // protects xs reuse (and covers initial Ws load)
    for (int i = threadIdx.x; i < 512; i += 256) {
      int gi = row0 * 128 + i;
      xs[i] = (gi < n * 128) ? x[gi] : 0.0f;
    }
    __syncthreads();
    float acc = 0.0f;
    #pragma unroll
    for (int k = 0; k < 128; ++k) acc += xs[r * 128 + k] * Ws[k * 64 + c];
    int row = row0 + r;
    if (row < n) h1[row * 64 + c] = acc;
  }
}

// out[i] = sum_{e: dst=i} dinv[src]*dinv[i]*h[src] + h[i]*dinv[i]^2  (+ optional bias+tanh)
// One wave per node; 64 lanes = 64 features.
template <int EPI>
__global__ __launch_bounds__(256) void agg_kernel(const float* __restrict__ h,
    const int* __restrict__ off, const int* __restrict__ csr,
    const float* __restrict__ dinv, const float* __restrict__ bias,
    float* __restrict__ out, int n) {
  int node = blockIdx.x * 4 + (threadIdx.x >> 6);
  if (node >= n) return;
  int lane = threadIdx.x & 63;
  float di = dinv[node];
  float acc = h[node * 64 + lane] * (di * di);  // self-loop term
  int e0 = off[node], e1 = off[node + 1];
  for (int ee = e0; ee < e1; ++ee) {
    int s = csr[ee];
    acc += (dinv[s] * di) * h[s * 64 + lane];
  }
  if (EPI) acc = tanhf(acc + bias[lane]);
  out[node * 64 + lane] = acc;
}

// mean = agg@Wm+bm ; logvar = agg@Wv+bv ; z = noise*exp(0.5*logvar)+mean
__global__ __launch_bounds__(256) void final_kernel(const float* __restrict__ agg,
    const float* __restrict__ Wm, const float* __restrict__ bm,
    const float* __restrict__ Wv, const float* __restrict__ bv,
    const float* __restrict__ noise, float* __restrict__ outZ,
    float* __restrict__ outM, float* __restrict__ outLv, int n) {
  __shared__ float WmS[64 * 32];
  __shared__ float WvS[64 * 32];
  __shared__ float aggS[8 * 64];
  for (int i = threadIdx.x; i < 64 * 32; i += 256) { WmS[i] = Wm[i]; WvS[i] = Wv[i]; }
  int row0 = blockIdx.x * 8;
  for (int i = threadIdx.x; i < 512; i += 256) {
    int gi = row0 * 64 + i;
    aggS[i] = (gi < n * 64) ? agg[gi] : 0.0f;
  }
  __syncthreads();
  int c = threadIdx.x & 31;
  int r = threadIdx.x >> 5;
  float m = bm[c], v = bv[c];
  #pragma unroll
  for (int k = 0; k < 64; ++k) {
    float a = aggS[r * 64 + k];
    m += a * WmS[k * 32 + c];
    v += a * WvS[k * 32 + c];
  }
  int row = row0 + r;
  if (row < n) {
    int oi = row * 32 + c;
    float z = noise[oi] * expf(0.5f * v) + m;
    outZ[oi] = z;
    outM[oi] = m;
    outLv[oi] = v;
  }
}

extern "C" void kernel_launch(void* const* d_in, const int* in_sizes, int n_in,
                              void* d_out, int out_size, void* d_ws, size_t ws_size,
                              hipStream_t stream) {
  const float* x    = (const float*)d_in[0];
  const int*  edge  = (const int*)d_in[1];
  const float* W1   = (const float*)d_in[2];
  const float* b1   = (const float*)d_in[3];
  const float* Wm   = (const float*)d_in[4];
  const float* bm   = (const float*)d_in[5];
  const float* Wv   = (const float*)d_in[6];
  const float* bv   = (const float*)d_in[7];
  const float* noise= (const float*)d_in[8];
  int n = in_sizes[0] / 128;   // 100000
  int e = in_sizes[1] / 2;     // 1200000
  const int* src = edge;
  const int* dst = edge + e;

  // workspace layout (4B units)
  int* cnt  = (int*)d_ws;          // n
  int* off  = cnt + n;             // n+4 (padded)
  int* cur  = off + (n + 4);       // n
  int* bsum = cur + n;             // 128
  float* dinv = (float*)(bsum + 128);  // n
  int* csr  = (int*)(dinv + n);    // e
  float* bufA = (float*)(csr + e); // n*64  (h1, later agg2)
  float* bufB = bufA + (size_t)n * 64;  // n*64 (h)

  float* outZ  = (float*)d_out;
  float* outM  = outZ + (size_t)n * 32;
  float* outLv = outM + (size_t)n * 32;

  int nb = (n + 1023) / 1024;  // 98 <= 128

  zero_kernel<<<(n + 255) / 256, 256, 0, stream>>>(cnt, n);
  hist_kernel<<<(e + 255) / 256, 256, 0, stream>>>(dst, cnt, e);
  scan_part_kernel<<<nb, 256, 0, stream>>>(cnt, off, bsum, n);
  scan_blocks_kernel<<<1, 64, 0, stream>>>(bsum, nb);
  scan_add_kernel<<<(n + 255) / 256, 256, 0, stream>>>(off, bsum, cnt, cur, dinv, n, e);
  fill_kernel<<<(e + 255) / 256, 256, 0, stream>>>(src, dst, cur, csr, e);
  gemm1_kernel<<<2560, 256, 0, stream>>>(x, W1, bufA, n);
  agg_kernel<1><<<(n + 3) / 4, 256, 0, stream>>>(bufA, off, csr, dinv, b1, bufB, n);
  agg_kernel<0><<<(n + 3) / 4, 256, 0, stream>>>(bufB, off, csr, dinv, b1, bufA, n);
  final_kernel<<<(n + 7) / 8, 256, 0, stream>>>(bufA, Wm, bm, Wv, bv, noise, outZ, outM, outLv, n);
}

// Round 2
// 311.350 us; speedup vs baseline: 1.6489x; 1.6489x over previous
//
#include <hip/hip_runtime.h>
#include <math.h>

// ---------- helpers ----------

__device__ __forceinline__ unsigned int pack_bf16(float a, float b) {
  unsigned int ua = __float_as_uint(a);
  ua += 0x7FFFu + ((ua >> 16) & 1u);
  unsigned int ub = __float_as_uint(b);
  ub += 0x7FFFu + ((ub >> 16) & 1u);
  return (ua >> 16) | (ub & 0xFFFF0000u);
}

// acc[0..7] += w * bf16x8(hv)
__device__ __forceinline__ void acc8(float* acc, uint4 hv, float w) {
  unsigned int u[4] = {hv.x, hv.y, hv.z, hv.w};
#pragma unroll
  for (int i = 0; i < 4; ++i) {
    float lo = __uint_as_float(u[i] << 16);
    float hi = __uint_as_float(u[i] & 0xFFFF0000u);
    acc[2 * i]     = fmaf(w, lo, acc[2 * i]);
    acc[2 * i + 1] = fmaf(w, hi, acc[2 * i + 1]);
  }
}

__device__ __forceinline__ void fma4(float4& acc, float s, const float4& w) {
  acc.x = fmaf(s, w.x, acc.x);
  acc.y = fmaf(s, w.y, acc.y);
  acc.z = fmaf(s, w.z, acc.z);
  acc.w = fmaf(s, w.w, acc.w);
}

// ---------- CSR build ----------

__global__ void zero_kernel(int* __restrict__ p, int n) {
  int i = blockIdx.x * blockDim.x + threadIdx.x;
  if (i < n) p[i] = 0;
}

__global__ void hist_kernel(const int* __restrict__ dst, int* __restrict__ cnt, int e) {
  int i = blockIdx.x * blockDim.x + threadIdx.x;
  if (i < e) atomicAdd(&cnt[dst[i]], 1);
}

__global__ void scan_part_kernel(const int* __restrict__ cnt, int* __restrict__ off,
                                 int* __restrict__ bsum, int n) {
  __shared__ int s[256];
  int t = threadIdx.x;
  int base = blockIdx.x * 1024;
  int idx = base + t * 4;
  int v0 = (idx + 0 < n) ? cnt[idx + 0] : 0;
  int v1 = (idx + 1 < n) ? cnt[idx + 1] : 0;
  int v2 = (idx + 2 < n) ? cnt[idx + 2] : 0;
  int v3 = (idx + 3 < n) ? cnt[idx + 3] : 0;
  int tsum = v0 + v1 + v2 + v3;
  s[t] = tsum;
  __syncthreads();
  for (int ofs = 1; ofs < 256; ofs <<= 1) {
    int add = (t >= ofs) ? s[t - ofs] : 0;
    __syncthreads();
    s[t] += add;
    __syncthreads();
  }
  int ex = s[t] - tsum;
  if (idx + 0 < n) off[idx + 0] = ex;
  if (idx + 1 < n) off[idx + 1] = ex + v0;
  if (idx + 2 < n) off[idx + 2] = ex + v0 + v1;
  if (idx + 3 < n) off[idx + 3] = ex + v0 + v1 + v2;
  if (t == 255) bsum[blockIdx.x] = s[255];
}

// parallel exclusive scan of up to 128 block sums
__global__ void scan_blocks_kernel(int* __restrict__ bsum, int nb) {
  __shared__ int s[128];
  int t = threadIdx.x;
  int v = (t < nb) ? bsum[t] : 0;
  s[t] = v;
  __syncthreads();
  for (int ofs = 1; ofs < 128; ofs <<= 1) {
    int add = (t >= ofs) ? s[t - ofs] : 0;
    __syncthreads();
    s[t] += add;
    __syncthreads();
  }
  if (t < nb) bsum[t] = s[t] - v;
}

__global__ void scan_add_kernel(int* __restrict__ off, const int* __restrict__ bsum,
                                const int* __restrict__ cnt, int* __restrict__ cur,
                                float* __restrict__ dinv, int n, int e) {
  int i = blockIdx.x * blockDim.x + threadIdx.x;
  if (i < n) {
    int o = off[i] + bsum[i >> 10];
    off[i] = o;
    cur[i] = o;
    dinv[i] = rsqrtf((float)(cnt[i] + 1));
  }
  if (i == 0) off[n] = e;
}

__global__ void fill_kernel(const int* __restrict__ src, const int* __restrict__ dst,
                            int* __restrict__ cur, int* __restrict__ csr, int e) {
  int i = blockIdx.x * blockDim.x + threadIdx.x;
  if (i < e) {
    int d = dst[i];
    int pos = atomicAdd(&cur[d], 1);
    csr[pos] = src[i];
  }
}

// ---------- h1 = x @ W1, output bf16 ----------
// x: [n,128] f32, W1: [128,64] f32 row-major, h1: [n,64] bf16 (as uint pairs)
__global__ __launch_bounds__(256) void gemm1_kernel(const float* __restrict__ x,
    const float* __restrict__ W1, unsigned int* __restrict__ h1, int n) {
  __shared__ float Ws[128 * 64];        // 32 KB
  __shared__ float xs[64 * 128];        // 32 KB, float4-slot XOR swizzle
  // load Ws (coalesced float4)
  for (int i = threadIdx.x; i < 128 * 16; i += 256)
    ((float4*)Ws)[i] = ((const float4*)W1)[i];
  int row0 = blockIdx.x * 64;
  int nrow = n - row0; if (nrow > 64) nrow = 64;
  // load xs tile with swizzle: slot(r,kq) = r*32 + (kq ^ ((r>>2)&3))
  for (int i = threadIdx.x; i < 64 * 32; i += 256) {
    int r = i >> 5, kq = i & 31;
    float4 v = make_float4(0.f, 0.f, 0.f, 0.f);
    if (r < nrow) v = ((const float4*)(x + (size_t)(row0 + r) * 128))[kq];
    int slot = r * 32 + (kq ^ ((r >> 2) & 3));
    *(float4*)&xs[slot * 4] = v;
  }
  __syncthreads();
  int c4 = (threadIdx.x & 15) * 4;
  int r4 = (threadIdx.x >> 4) * 4;
  float4 acc[4];
#pragma unroll
  for (int i = 0; i < 4; ++i) acc[i] = make_float4(0.f, 0.f, 0.f, 0.f);
#pragma unroll 4
  for (int kq = 0; kq < 32; ++kq) {
    float4 xv[4], wv[4];
#pragma unroll
    for (int i = 0; i < 4; ++i) {
      int r = r4 + i;
      int slot = r * 32 + (kq ^ ((r >> 2) & 3));
      xv[i] = *(const float4*)&xs[slot * 4];
    }
#pragma unroll
    for (int q = 0; q < 4; ++q) wv[q] = *(const float4*)&Ws[(kq * 4 + q) * 64 + c4];
#pragma unroll
    for (int i = 0; i < 4; ++i) {
      fma4(acc[i], xv[i].x, wv[0]);
      fma4(acc[i], xv[i].y, wv[1]);
      fma4(acc[i], xv[i].z, wv[2]);
      fma4(acc[i], xv[i].w, wv[3]);
    }
  }
#pragma unroll
  for (int i = 0; i < 4; ++i) {
    int row = row0 + r4 + i;
    if (row < n) {
      uint2 pv;
      pv.x = pack_bf16(acc[i].x, acc[i].y);
      pv.y = pack_bf16(acc[i].z, acc[i].w);
      ((uint2*)h1)[(size_t)row * 16 + (threadIdx.x & 15)] = pv;
    }
  }
}

// ---------- aggregation: out[i] = sum_{e:dst=i} dinv[s]*dinv[i]*h[s] + h[i]*dinv[i]^2 ----------
// h: [n][64] bf16 (8 uint4 per row). Wave = 8 edge-slots x 8 feature-lanes.
// EPI=1: out = bf16(tanh(agg + bias)); EPI=0: out = f32 agg.
template <int EPI>
__global__ __launch_bounds__(256) void agg_kernel(const uint4* __restrict__ h4,
    const int* __restrict__ off, const int* __restrict__ csr,
    const float* __restrict__ dinv, const float* __restrict__ bias,
    void* __restrict__ out, int n) {
  int node = blockIdx.x * 4 + (threadIdx.x >> 6);
  if (node >= n) return;
  int lane = threadIdx.x & 63;
  int j = lane >> 3;   // edge slot 0..7
  int l = lane & 7;    // feature group (8 bf16 = 16B)
  float di = dinv[node];
  float acc[8];
#pragma unroll
  for (int i = 0; i < 8; ++i) acc[i] = 0.f;
  if (j == 0) {  // self loop
    uint4 hv = h4[(size_t)node * 8 + l];
    acc8(acc, hv, di * di);
  }
  int e1 = off[node + 1];
  for (int ee = off[node] + j; ee < e1; ee += 8) {
    int s = csr[ee];
    float w = dinv[s] * di;
    uint4 hv = h4[(size_t)s * 8 + l];
    acc8(acc, hv, w);
  }
  // reduce across the 8 edge slots
#pragma unroll
  for (int m = 8; m < 64; m <<= 1) {
#pragma unroll
    for (int i = 0; i < 8; ++i) acc[i] += __shfl_xor(acc[i], m);
  }
  if (j == 0) {
    if (EPI) {
      float4 b0 = ((const float4*)bias)[l * 2];
      float4 b1 = ((const float4*)bias)[l * 2 + 1];
      float v0 = tanhf(acc[0] + b0.x), v1 = tanhf(acc[1] + b0.y);
      float v2 = tanhf(acc[2] + b0.z), v3 = tanhf(acc[3] + b0.w);
      float v4 = tanhf(acc[4] + b1.x), v5 = tanhf(acc[5] + b1.y);
      float v6 = tanhf(acc[6] + b1.z), v7 = tanhf(acc[7] + b1.w);
      uint4 pv;
      pv.x = pack_bf16(v0, v1); pv.y = pack_bf16(v2, v3);
      pv.z = pack_bf16(v4, v5); pv.w = pack_bf16(v6, v7);
      ((uint4*)out)[(size_t)node * 8 + l] = pv;
    } else {
      float4 o0 = make_float4(acc[0], acc[1], acc[2], acc[3]);
      float4 o1 = make_float4(acc[4], acc[5], acc[6], acc[7]);
      ((float4*)out)[(size_t)node * 16 + l * 2]     = o0;
      ((float4*)out)[(size_t)node * 16 + l * 2 + 1] = o1;
    }
  }
}

// ---------- final: mean/logvar GEMMs + reparam ----------
// agg: [n][64] f32; Wm,Wv: [64][32]; tile 64 rows x 32 cols.
__global__ __launch_bounds__(256) void final_kernel(const float* __restrict__ agg,
    const float* __restrict__ Wm, const float* __restrict__ bm,
    const float* __restrict__ Wv, const float* __restrict__ bv,
    const float* __restrict__ noise, float* __restrict__ outZ,
    float* __restrict__ outM, float* __restrict__ outLv, int n) {
  __shared__ float WmS[64 * 32];
  __shared__ float WvS[64 * 32];
  __shared__ float aggS[64 * 68];  // stride 68 to break bank conflicts
  for (int i = threadIdx.x; i < 64 * 8; i += 256) {
    ((float4*)WmS)[i] = ((const float4*)Wm)[i];
    ((float4*)WvS)[i] = ((const float4*)Wv)[i];
  }
  int row0 = blockIdx.x * 64;
  int nrow = n - row0; if (nrow > 64) nrow = 64;
  for (int i = threadIdx.x; i < 64 * 16; i += 256) {
    int r = i >> 4, kq = i & 15;
    float4 v = make_float4(0.f, 0.f, 0.f, 0.f);
    if (r < nrow) v = ((const float4*)(agg + (size_t)(row0 + r) * 64))[kq];
    *(float4*)&aggS[r * 68 + kq * 4] = v;
  }
  __syncthreads();
  int c4 = (threadIdx.x & 7) * 4;
  int r2 = (threadIdx.x >> 3) * 2;
  float4 am[2], av[2];
#pragma unroll
  for (int i = 0; i < 2; ++i) {
    am[i] = make_float4(0.f, 0.f, 0.f, 0.f);
    av[i] = make_float4(0.f, 0.f, 0.f, 0.f);
  }
#pragma unroll 4
  for (int kq = 0; kq < 16; ++kq) {
    float4 xa[2], wm[4], wv[4];
#pragma unroll
    for (int i = 0; i < 2; ++i) xa[i] = *(const float4*)&aggS[(r2 + i) * 68 + kq * 4];
#pragma unroll
    for (int q = 0; q < 4; ++q) {
      wm[q] = *(const float4*)&WmS[(kq * 4 + q) * 32 + c4];
      wv[q] = *(const float4*)&WvS[(kq * 4 + q) * 32 + c4];
    }
#pragma unroll
    for (int i = 0; i < 2; ++i) {
      fma4(am[i], xa[i].x, wm[0]); fma4(am[i], xa[i].y, wm[1]);
      fma4(am[i], xa[i].z, wm[2]); fma4(am[i], xa[i].w, wm[3]);
      fma4(av[i], xa[i].x, wv[0]); fma4(av[i], xa[i].y, wv[1]);
      fma4(av[i], xa[i].z, wv[2]); fma4(av[i], xa[i].w, wv[3]);
    }
  }
  float4 bmv = *(const float4*)&bm[c4];
  float4 bvv = *(const float4*)&bv[c4];
#pragma unroll
  for (int i = 0; i < 2; ++i) {
    int row = row0 + r2 + i;
    if (row < n) {
      float4 m = am[i]; m.x += bmv.x; m.y += bmv.y; m.z += bmv.z; m.w += bmv.w;
      float4 v = av[i]; v.x += bvv.x; v.y += bvv.y; v.z += bvv.z; v.w += bvv.w;
      size_t oi = (size_t)row * 8 + (threadIdx.x & 7);
      float4 nz = ((const float4*)noise)[oi];
      float4 z;
      z.x = fmaf(nz.x, expf(0.5f * v.x), m.x);
      z.y = fmaf(nz.y, expf(0.5f * v.y), m.y);
      z.z = fmaf(nz.z, expf(0.5f * v.z), m.z);
      z.w = fmaf(nz.w, expf(0.5f * v.w), m.w);
      ((float4*)outZ)[oi] = z;
      ((float4*)outM)[oi] = m;
      ((float4*)outLv)[oi] = v;
    }
  }
}

// ---------- launch ----------

extern "C" void kernel_launch(void* const* d_in, const int* in_sizes, int n_in,
                              void* d_out, int out_size, void* d_ws, size_t ws_size,
                              hipStream_t stream) {
  const float* x     = (const float*)d_in[0];
  const int*   edge  = (const int*)d_in[1];
  const float* W1    = (const float*)d_in[2];
  const float* b1    = (const float*)d_in[3];
  const float* Wm    = (const float*)d_in[4];
  const float* bm    = (const float*)d_in[5];
  const float* Wv    = (const float*)d_in[6];
  const float* bv    = (const float*)d_in[7];
  const float* noise = (const float*)d_in[8];
  int n = in_sizes[0] / 128;
  int e = in_sizes[1] / 2;
  const int* src = edge;
  const int* dst = edge + e;

  // workspace layout (int units, 16B-aligned segments)
  int* cnt  = (int*)d_ws;                       // n
  int* off  = cnt + ((n + 3) & ~3);             // n+1 (+pad)
  int* cur  = off + ((n + 7) & ~3);             // n
  int* bsum = cur + ((n + 3) & ~3);             // 128
  float* dinv = (float*)(bsum + 128);           // n
  int* csr  = (int*)(dinv + ((n + 3) & ~3));    // e
  unsigned int* h1b = (unsigned int*)(csr + ((e + 3) & ~3)); // n*32 uints (bf16 h1)
  unsigned int* hb  = h1b + (size_t)n * 32;                  // n*32 uints (bf16 h)
  float* aggf = (float*)(hb + (size_t)n * 32);               // n*64 f32

  float* outZ  = (float*)d_out;
  float* outM  = outZ + (size_t)n * 32;
  float* outLv = outM + (size_t)n * 32;

  int nb = (n + 1023) / 1024;

  zero_kernel<<<(n + 255) / 256, 256, 0, stream>>>(cnt, n);
  hist_kernel<<<(e + 255) / 256, 256, 0, stream>>>(dst, cnt, e);
  scan_part_kernel<<<nb, 256, 0, stream>>>(cnt, off, bsum, n);
  scan_blocks_kernel<<<1, 128, 0, stream>>>(bsum, nb);
  scan_add_kernel<<<(n + 255) / 256, 256, 0, stream>>>(off, bsum, cnt, cur, dinv, n, e);
  fill_kernel<<<(e + 255) / 256, 256, 0, stream>>>(src, dst, cur, csr, e);
  gemm1_kernel<<<(n + 63) / 64, 256, 0, stream>>>(x, W1, h1b, n);
  agg_kernel<1><<<(n + 3) / 4, 256, 0, stream>>>((const uint4*)h1b, off, csr, dinv, b1, hb, n);
  agg_kernel<0><<<(n + 3) / 4, 256, 0, stream>>>((const uint4*)hb, off, csr, dinv, b1, aggf, n);
  final_kernel<<<(n + 63) / 64, 256, 0, stream>>>(aggf, Wm, bm, Wv, bv, noise, outZ, outM, outLv, n);
}

// Round 3
// 260.609 us; speedup vs baseline: 1.9699x; 1.1947x over previous
//
#include <hip/hip_runtime.h>
#include <math.h>

// ---------- helpers ----------

__device__ __forceinline__ unsigned int pack_bf16(float a, float b) {
  unsigned int ua = __float_as_uint(a);
  ua += 0x7FFFu + ((ua >> 16) & 1u);
  unsigned int ub = __float_as_uint(b);
  ub += 0x7FFFu + ((ub >> 16) & 1u);
  return (ua >> 16) | (ub & 0xFFFF0000u);
}

// acc[0..7] += bf16x8(hv)
__device__ __forceinline__ void add8(float* acc, uint4 hv) {
  unsigned int u[4] = {hv.x, hv.y, hv.z, hv.w};
#pragma unroll
  for (int i = 0; i < 4; ++i) {
    acc[2 * i]     += __uint_as_float(u[i] << 16);
    acc[2 * i + 1] += __uint_as_float(u[i] & 0xFFFF0000u);
  }
}

__device__ __forceinline__ void fma4(float4& acc, float s, const float4& w) {
  acc.x = fmaf(s, w.x, acc.x);
  acc.y = fmaf(s, w.y, acc.y);
  acc.z = fmaf(s, w.z, acc.z);
  acc.w = fmaf(s, w.w, acc.w);
}

// ---------- bucketed CSR build ----------
// bucket = dst >> 6  (64 nodes per bucket). Cursor/count arrays padded 16 ints
// (one per 64B line) to avoid same-line atomic serialization.

__global__ void zero_kernel(int* __restrict__ p, int n) {
  int i = blockIdx.x * blockDim.x + threadIdx.x;
  if (i < n) p[i] = 0;
}

__global__ __launch_bounds__(256) void bucket_hist_kernel(const int* __restrict__ dst,
    int* __restrict__ bcnt, int e, int nb) {
  __shared__ int h[2048];
  for (int i = threadIdx.x; i < nb; i += 256) h[i] = 0;
  __syncthreads();
  for (int i = blockIdx.x * 256 + threadIdx.x; i < e; i += gridDim.x * 256)
    atomicAdd(&h[dst[i] >> 6], 1);
  __syncthreads();
  for (int i = threadIdx.x; i < nb; i += 256)
    if (h[i]) atomicAdd(&bcnt[i * 16], h[i]);
}

// single block: exclusive scan of nb bucket counts (nb <= 1792)
__global__ __launch_bounds__(256) void bucket_scan_kernel(const int* __restrict__ bcnt,
    int* __restrict__ boff, int* __restrict__ bcur, int* __restrict__ off,
    int nb, int n, int e) {
  __shared__ int s[256];
  int t = threadIdx.x;
  int base = t * 7;
  int v[7];
  int sum = 0;
#pragma unroll
  for (int k = 0; k < 7; ++k) {
    int i = base + k;
    v[k] = (i < nb) ? bcnt[i * 16] : 0;
    sum += v[k];
  }
  s[t] = sum;
  __syncthreads();
  for (int ofs = 1; ofs < 256; ofs <<= 1) {
    int add = (t >= ofs) ? s[t - ofs] : 0;
    __syncthreads();
    s[t] += add;
    __syncthreads();
  }
  int run = s[t] - sum;
#pragma unroll
  for (int k = 0; k < 7; ++k) {
    int i = base + k;
    if (i < nb) { boff[i] = run; bcur[i * 16] = run; }
    run += v[k];
  }
  if (t == 0) { boff[nb] = e; off[n] = e; }
}

__global__ void partition_kernel(const int* __restrict__ src, const int* __restrict__ dst,
    int* __restrict__ bcur, unsigned int* __restrict__ packed, int e) {
  int i = blockIdx.x * blockDim.x + threadIdx.x;
  if (i < e) {
    int s = src[i], d = dst[i];
    int b = d >> 6;
    int pos = atomicAdd(&bcur[b * 16], 1);
    packed[pos] = (unsigned int)s | ((unsigned int)(d & 63) << 20);
  }
}

// one wave per bucket: counting sort into CSR + per-node off + dinv
__global__ __launch_bounds__(64) void csr_build_kernel(const unsigned int* __restrict__ packed,
    const int* __restrict__ boff, int* __restrict__ off, float* __restrict__ dinv,
    int* __restrict__ csr, int n) {
  __shared__ int lh[64];
  __shared__ int lcur[64];
  int b = blockIdx.x;
  int t = threadIdx.x;
  int e0 = boff[b], e1 = boff[b + 1];
  lh[t] = 0;
  __syncthreads();
  for (int i = e0 + t; i < e1; i += 64) atomicAdd(&lh[(packed[i] >> 20) & 63], 1);
  __syncthreads();
  int cnt = lh[t];
  int incl = cnt;
#pragma unroll
  for (int ofs = 1; ofs < 64; ofs <<= 1) {
    int w = __shfl_up(incl, ofs);
    if (t >= ofs) incl += w;
  }
  int excl = incl - cnt;
  lcur[t] = excl;
  int node = b * 64 + t;
  if (node < n) {
    off[node] = e0 + excl;
    dinv[node] = rsqrtf((float)(cnt + 1));
  }
  __syncthreads();
  for (int i = e0 + t; i < e1; i += 64) {
    unsigned int p = packed[i];
    int dl = (p >> 20) & 63;
    int pos = atomicAdd(&lcur[dl], 1);
    csr[e0 + pos] = (int)(p & 0xFFFFFu);
  }
}

// ---------- h1' = dinv * (x @ W1), output bf16 ----------
__global__ __launch_bounds__(256) void gemm1_kernel(const float* __restrict__ x,
    const float* __restrict__ W1, const float* __restrict__ dinv,
    unsigned int* __restrict__ h1, int n) {
  __shared__ float Ws[128 * 64];        // 32 KB
  __shared__ float xs[64 * 128];        // 32 KB, float4-slot XOR swizzle
  for (int i = threadIdx.x; i < 128 * 16; i += 256)
    ((float4*)Ws)[i] = ((const float4*)W1)[i];
  int row0 = blockIdx.x * 64;
  int nrow = n - row0; if (nrow > 64) nrow = 64;
  for (int i = threadIdx.x; i < 64 * 32; i += 256) {
    int r = i >> 5, kq = i & 31;
    float4 v = make_float4(0.f, 0.f, 0.f, 0.f);
    if (r < nrow) v = ((const float4*)(x + (size_t)(row0 + r) * 128))[kq];
    int slot = r * 32 + (kq ^ ((r >> 2) & 3));
    *(float4*)&xs[slot * 4] = v;
  }
  __syncthreads();
  int c4 = (threadIdx.x & 15) * 4;
  int r4 = (threadIdx.x >> 4) * 4;
  float4 acc[4];
#pragma unroll
  for (int i = 0; i < 4; ++i) acc[i] = make_float4(0.f, 0.f, 0.f, 0.f);
#pragma unroll 4
  for (int kq = 0; kq < 32; ++kq) {
    float4 xv[4], wv[4];
#pragma unroll
    for (int i = 0; i < 4; ++i) {
      int r = r4 + i;
      int slot = r * 32 + (kq ^ ((r >> 2) & 3));
      xv[i] = *(const float4*)&xs[slot * 4];
    }
#pragma unroll
    for (int q = 0; q < 4; ++q) wv[q] = *(const float4*)&Ws[(kq * 4 + q) * 64 + c4];
#pragma unroll
    for (int i = 0; i < 4; ++i) {
      fma4(acc[i], xv[i].x, wv[0]);
      fma4(acc[i], xv[i].y, wv[1]);
      fma4(acc[i], xv[i].z, wv[2]);
      fma4(acc[i], xv[i].w, wv[3]);
    }
  }
#pragma unroll
  for (int i = 0; i < 4; ++i) {
    int row = row0 + r4 + i;
    if (row < n) {
      float dv = dinv[row];
      uint2 pv;
      pv.x = pack_bf16(dv * acc[i].x, dv * acc[i].y);
      pv.y = pack_bf16(dv * acc[i].z, dv * acc[i].w);
      ((uint2*)h1)[(size_t)row * 16 + (threadIdx.x & 15)] = pv;
    }
  }
}

// ---------- aggregation ----------
// h4 rows are dinv-prefolded: h'[s] = dinv[s]*h[s].
// acc = h'[node] + sum_{e:dst=node} h'[src];  result_feat = dinv[node]*acc.
// EPI=1: out = bf16( dinv[node] * tanh(result + bias) )   (fold for next layer)
// EPI=0: out = bf16( result )
template <int EPI>
__global__ __launch_bounds__(256) void agg_kernel(const uint4* __restrict__ h4,
    const int* __restrict__ off, const int* __restrict__ csr,
    const float* __restrict__ dinv, const float* __restrict__ bias,
    unsigned int* __restrict__ out, int n) {
  int node = blockIdx.x * 4 + (threadIdx.x >> 6);
  if (node >= n) return;
  int lane = threadIdx.x & 63;
  int j = lane >> 3;   // edge slot 0..7
  int l = lane & 7;    // feature group (8 bf16 = 16B)
  float acc[8];
#pragma unroll
  for (int i = 0; i < 8; ++i) acc[i] = 0.f;
  if (j == 0) add8(acc, h4[(size_t)node * 8 + l]);  // self loop
  int e1 = off[node + 1];
  for (int ee = off[node] + j; ee < e1; ee += 8) {
    int s = csr[ee];
    add8(acc, h4[(size_t)s * 8 + l]);
  }
#pragma unroll
  for (int m = 8; m < 64; m <<= 1) {
#pragma unroll
    for (int i = 0; i < 8; ++i) acc[i] += __shfl_xor(acc[i], m);
  }
  if (j == 0) {
    float di = dinv[node];
    uint4 pv;
    if (EPI) {
      float4 b0 = ((const float4*)bias)[l * 2];
      float4 b1 = ((const float4*)bias)[l * 2 + 1];
      float v0 = di * tanhf(fmaf(di, acc[0], b0.x));
      float v1 = di * tanhf(fmaf(di, acc[1], b0.y));
      float v2 = di * tanhf(fmaf(di, acc[2], b0.z));
      float v3 = di * tanhf(fmaf(di, acc[3], b0.w));
      float v4 = di * tanhf(fmaf(di, acc[4], b1.x));
      float v5 = di * tanhf(fmaf(di, acc[5], b1.y));
      float v6 = di * tanhf(fmaf(di, acc[6], b1.z));
      float v7 = di * tanhf(fmaf(di, acc[7], b1.w));
      pv.x = pack_bf16(v0, v1); pv.y = pack_bf16(v2, v3);
      pv.z = pack_bf16(v4, v5); pv.w = pack_bf16(v6, v7);
    } else {
      pv.x = pack_bf16(di * acc[0], di * acc[1]);
      pv.y = pack_bf16(di * acc[2], di * acc[3]);
      pv.z = pack_bf16(di * acc[4], di * acc[5]);
      pv.w = pack_bf16(di * acc[6], di * acc[7]);
    }
    ((uint4*)out)[(size_t)node * 8 + l] = pv;
  }
}

// ---------- final: mean/logvar GEMMs + reparam ----------
// agg: [n][64] bf16; Wm,Wv: [64][32]; tile 64 rows x 32 cols.
__global__ __launch_bounds__(256) void final_kernel(const unsigned int* __restrict__ aggb,
    const float* __restrict__ Wm, const float* __restrict__ bm,
    const float* __restrict__ Wv, const float* __restrict__ bv,
    const float* __restrict__ noise, float* __restrict__ outZ,
    float* __restrict__ outM, float* __restrict__ outLv, int n) {
  __shared__ float WmS[64 * 32];
  __shared__ float WvS[64 * 32];
  __shared__ float aggS[64 * 68];  // stride 68 breaks bank conflicts
  for (int i = threadIdx.x; i < 64 * 8; i += 256) {
    ((float4*)WmS)[i] = ((const float4*)Wm)[i];
    ((float4*)WvS)[i] = ((const float4*)Wv)[i];
  }
  int row0 = blockIdx.x * 64;
  int nrow = n - row0; if (nrow > 64) nrow = 64;
  for (int i = threadIdx.x; i < 64 * 16; i += 256) {
    int r = i >> 4, g = i & 15;
    uint2 u = make_uint2(0u, 0u);
    if (r < nrow) u = ((const uint2*)aggb)[(size_t)(row0 + r) * 16 + g];
    float* d = &aggS[r * 68 + g * 4];
    d[0] = __uint_as_float(u.x << 16);
    d[1] = __uint_as_float(u.x & 0xFFFF0000u);
    d[2] = __uint_as_float(u.y << 16);
    d[3] = __uint_as_float(u.y & 0xFFFF0000u);
  }
  __syncthreads();
  int c4 = (threadIdx.x & 7) * 4;
  int r2 = (threadIdx.x >> 3) * 2;
  float4 am[2], av[2];
#pragma unroll
  for (int i = 0; i < 2; ++i) {
    am[i] = make_float4(0.f, 0.f, 0.f, 0.f);
    av[i] = make_float4(0.f, 0.f, 0.f, 0.f);
  }
#pragma unroll 4
  for (int kq = 0; kq < 16; ++kq) {
    float4 xa[2], wm[4], wv[4];
#pragma unroll
    for (int i = 0; i < 2; ++i) xa[i] = *(const float4*)&aggS[(r2 + i) * 68 + kq * 4];
#pragma unroll
    for (int q = 0; q < 4; ++q) {
      wm[q] = *(const float4*)&WmS[(kq * 4 + q) * 32 + c4];
      wv[q] = *(const float4*)&WvS[(kq * 4 + q) * 32 + c4];
    }
#pragma unroll
    for (int i = 0; i < 2; ++i) {
      fma4(am[i], xa[i].x, wm[0]); fma4(am[i], xa[i].y, wm[1]);
      fma4(am[i], xa[i].z, wm[2]); fma4(am[i], xa[i].w, wm[3]);
      fma4(av[i], xa[i].x, wv[0]); fma4(av[i], xa[i].y, wv[1]);
      fma4(av[i], xa[i].z, wv[2]); fma4(av[i], xa[i].w, wv[3]);
    }
  }
  float4 bmv = *(const float4*)&bm[c4];
  float4 bvv = *(const float4*)&bv[c4];
#pragma unroll
  for (int i = 0; i < 2; ++i) {
    int row = row0 + r2 + i;
    if (row < n) {
      float4 m = am[i]; m.x += bmv.x; m.y += bmv.y; m.z += bmv.z; m.w += bmv.w;
      float4 v = av[i]; v.x += bvv.x; v.y += bvv.y; v.z += bvv.z; v.w += bvv.w;
      size_t oi = (size_t)row * 8 + (threadIdx.x & 7);
      float4 nz = ((const float4*)noise)[oi];
      float4 z;
      z.x = fmaf(nz.x, expf(0.5f * v.x), m.x);
      z.y = fmaf(nz.y, expf(0.5f * v.y), m.y);
      z.z = fmaf(nz.z, expf(0.5f * v.z), m.z);
      z.w = fmaf(nz.w, expf(0.5f * v.w), m.w);
      ((float4*)outZ)[oi] = z;
      ((float4*)outM)[oi] = m;
      ((float4*)outLv)[oi] = v;
    }
  }
}

// ---------- launch ----------

extern "C" void kernel_launch(void* const* d_in, const int* in_sizes, int n_in,
                              void* d_out, int out_size, void* d_ws, size_t ws_size,
                              hipStream_t stream) {
  const float* x     = (const float*)d_in[0];
  const int*   edge  = (const int*)d_in[1];
  const float* W1    = (const float*)d_in[2];
  const float* b1    = (const float*)d_in[3];
  const float* Wm    = (const float*)d_in[4];
  const float* bm    = (const float*)d_in[5];
  const float* Wv    = (const float*)d_in[6];
  const float* bv    = (const float*)d_in[7];
  const float* noise = (const float*)d_in[8];
  int n = in_sizes[0] / 128;
  int e = in_sizes[1] / 2;
  const int* src = edge;
  const int* dst = edge + e;
  int nb = (n + 63) >> 6;   // 1563 buckets of 64 nodes

  // workspace layout (int units, 16B-aligned segments)
  int* bcnt = (int*)d_ws;                          // nb*16 (padded: 1 per 64B line)
  int* bcur = bcnt + nb * 16;                      // nb*16
  int* boff = bcur + nb * 16;                      // nb+1 (+pad)
  int* off  = boff + ((nb + 4) & ~3);              // n+1 (+pad)
  float* dinv = (float*)(off + ((n + 4) & ~3));    // n
  unsigned int* packed = (unsigned int*)(dinv + ((n + 3) & ~3)); // e
  int* csr  = (int*)(packed + ((e + 3) & ~3));     // e
  unsigned int* h1b = (unsigned int*)(csr + ((e + 3) & ~3)); // n*32 (bf16 h1')
  unsigned int* hb  = h1b + (size_t)n * 32;                  // n*32 (bf16 h')
  unsigned int* aggb = hb + (size_t)n * 32;                  // n*32 (bf16 agg2)

  float* outZ  = (float*)d_out;
  float* outM  = outZ + (size_t)n * 32;
  float* outLv = outM + (size_t)n * 32;

  zero_kernel<<<(nb * 16 + 255) / 256, 256, 0, stream>>>(bcnt, nb * 16);
  bucket_hist_kernel<<<128, 256, 0, stream>>>(dst, bcnt, e, nb);
  bucket_scan_kernel<<<1, 256, 0, stream>>>(bcnt, boff, bcur, off, nb, n, e);
  partition_kernel<<<(e + 255) / 256, 256, 0, stream>>>(src, dst, bcur, packed, e);
  csr_build_kernel<<<nb, 64, 0, stream>>>(packed, boff, off, dinv, csr, n);
  gemm1_kernel<<<(n + 63) / 64, 256, 0, stream>>>(x, W1, dinv, h1b, n);
  agg_kernel<1><<<(n + 3) / 4, 256, 0, stream>>>((const uint4*)h1b, off, csr, dinv, b1, hb, n);
  agg_kernel<0><<<(n + 3) / 4, 256, 0, stream>>>((const uint4*)hb, off, csr, dinv, b1, aggb, n);
  final_kernel<<<(n + 63) / 64, 256, 0, stream>>>(aggb, Wm, bm, Wv, bv, noise, outZ, outM, outLv, n);
}

// Round 4
// 258.543 us; speedup vs baseline: 1.9856x; 1.0080x over previous
//
#include <hip/hip_runtime.h>
#include <math.h>

// ---------- helpers ----------

__device__ __forceinline__ unsigned int pack_bf16(float a, float b) {
  unsigned int ua = __float_as_uint(a);
  ua += 0x7FFFu + ((ua >> 16) & 1u);
  unsigned int ub = __float_as_uint(b);
  ub += 0x7FFFu + ((ub >> 16) & 1u);
  return (ua >> 16) | (ub & 0xFFFF0000u);
}

// acc[0..7] += bf16x8(hv)
__device__ __forceinline__ void add8(float* acc, uint4 hv) {
  unsigned int u[4] = {hv.x, hv.y, hv.z, hv.w};
#pragma unroll
  for (int i = 0; i < 4; ++i) {
    acc[2 * i]     += __uint_as_float(u[i] << 16);
    acc[2 * i + 1] += __uint_as_float(u[i] & 0xFFFF0000u);
  }
}

__device__ __forceinline__ void fma4(float4& acc, float s, const float4& w) {
  acc.x = fmaf(s, w.x, acc.x);
  acc.y = fmaf(s, w.y, acc.y);
  acc.z = fmaf(s, w.z, acc.z);
  acc.w = fmaf(s, w.w, acc.w);
}

// ---------- bucketed CSR build ----------
// bucket = dst >> 6  (64 nodes per bucket). Cursor/count arrays padded 16 ints
// (one per 64B line). Bucket b is OWNED by XCD group b&7: only blocks with
// blockIdx%8==b&7 write its packed region / cursor, so those lines stay in one
// XCD's L2 (round-robin dispatch assumption — perf-only, not correctness).

__global__ void zero_kernel(int* __restrict__ p, int n) {
  int i = blockIdx.x * blockDim.x + threadIdx.x;
  if (i < n) p[i] = 0;
}

__global__ __launch_bounds__(256) void bucket_hist_kernel(const int* __restrict__ dst,
    int* __restrict__ bcnt, int e, int nb) {
  __shared__ int h[2048];
  for (int i = threadIdx.x; i < nb; i += 256) h[i] = 0;
  __syncthreads();
  for (int i = blockIdx.x * 256 + threadIdx.x; i < e; i += gridDim.x * 256)
    atomicAdd(&h[dst[i] >> 6], 1);
  __syncthreads();
  for (int i = threadIdx.x; i < nb; i += 256)
    if (h[i]) atomicAdd(&bcnt[i * 16], h[i]);
}

// single block: exclusive scan of nb bucket counts (nb <= 1792)
__global__ __launch_bounds__(256) void bucket_scan_kernel(const int* __restrict__ bcnt,
    int* __restrict__ boff, int* __restrict__ bcur, int* __restrict__ off,
    int nb, int n, int e) {
  __shared__ int s[256];
  int t = threadIdx.x;
  int base = t * 7;
  int v[7];
  int sum = 0;
#pragma unroll
  for (int k = 0; k < 7; ++k) {
    int i = base + k;
    v[k] = (i < nb) ? bcnt[i * 16] : 0;
    sum += v[k];
  }
  s[t] = sum;
  __syncthreads();
  for (int ofs = 1; ofs < 256; ofs <<= 1) {
    int add = (t >= ofs) ? s[t - ofs] : 0;
    __syncthreads();
    s[t] += add;
    __syncthreads();
  }
  int run = s[t] - sum;
#pragma unroll
  for (int k = 0; k < 7; ++k) {
    int i = base + k;
    if (i < nb) { boff[i] = run; bcur[i * 16] = run; }
    run += v[k];
  }
  if (t == 0) { boff[nb] = e; off[n] = e; }
}

// XCD-grouped partition: block group g = blockIdx&7 handles only buckets with
// (b&7)==g; chunk = blockIdx>>3 selects the edge range it scans.
__global__ __launch_bounds__(256) void partition_kernel(const int* __restrict__ src,
    const int* __restrict__ dst, int* __restrict__ bcur,
    unsigned int* __restrict__ packed, int e, int nchunks) {
  int g = blockIdx.x & 7;
  int chunk = blockIdx.x >> 3;
  int per = (e + nchunks - 1) / nchunks;
  int i0 = chunk * per;
  int i1 = i0 + per; if (i1 > e) i1 = e;
  for (int i = i0 + threadIdx.x; i < i1; i += 256) {
    int d = dst[i];
    if (((d >> 6) & 7) != g) continue;
    int b = d >> 6;
    int pos = atomicAdd(&bcur[b * 16], 1);
    packed[pos] = (unsigned int)src[i] | ((unsigned int)(d & 63) << 20);
  }
}

// one wave per bucket: counting sort into CSR + per-node off + dinv.
// Block b lands on XCD b&7 (round-robin), same XCD that wrote packed[e0..e1).
__global__ __launch_bounds__(64) void csr_build_kernel(const unsigned int* __restrict__ packed,
    const int* __restrict__ boff, int* __restrict__ off, float* __restrict__ dinv,
    int* __restrict__ csr, int n) {
  __shared__ int lh[64];
  __shared__ int lcur[64];
  int b = blockIdx.x;
  int t = threadIdx.x;
  int e0 = boff[b], e1 = boff[b + 1];
  lh[t] = 0;
  __syncthreads();
  for (int i = e0 + t; i < e1; i += 64) atomicAdd(&lh[(packed[i] >> 20) & 63], 1);
  __syncthreads();
  int cnt = lh[t];
  int incl = cnt;
#pragma unroll
  for (int ofs = 1; ofs < 64; ofs <<= 1) {
    int w = __shfl_up(incl, ofs);
    if (t >= ofs) incl += w;
  }
  int excl = incl - cnt;
  lcur[t] = excl;
  int node = b * 64 + t;
  if (node < n) {
    off[node] = e0 + excl;
    dinv[node] = rsqrtf((float)(cnt + 1));
  }
  __syncthreads();
  for (int i = e0 + t; i < e1; i += 64) {
    unsigned int p = packed[i];
    int dl = (p >> 20) & 63;
    int pos = atomicAdd(&lcur[dl], 1);
    csr[e0 + pos] = (int)(p & 0xFFFFFu);
  }
}

// ---------- h1' = dinv * (x @ W1), output bf16 ----------
__global__ __launch_bounds__(256) void gemm1_kernel(const float* __restrict__ x,
    const float* __restrict__ W1, const float* __restrict__ dinv,
    unsigned int* __restrict__ h1, int n) {
  __shared__ float Ws[128 * 64];        // 32 KB
  __shared__ float xs[64 * 128];        // 32 KB, float4-slot XOR swizzle
  for (int i = threadIdx.x; i < 128 * 16; i += 256)
    ((float4*)Ws)[i] = ((const float4*)W1)[i];
  int row0 = blockIdx.x * 64;
  int nrow = n - row0; if (nrow > 64) nrow = 64;
  for (int i = threadIdx.x; i < 64 * 32; i += 256) {
    int r = i >> 5, kq = i & 31;
    float4 v = make_float4(0.f, 0.f, 0.f, 0.f);
    if (r < nrow) v = ((const float4*)(x + (size_t)(row0 + r) * 128))[kq];
    int slot = r * 32 + (kq ^ ((r >> 2) & 3));
    *(float4*)&xs[slot * 4] = v;
  }
  __syncthreads();
  int c4 = (threadIdx.x & 15) * 4;
  int r4 = (threadIdx.x >> 4) * 4;
  float4 acc[4];
#pragma unroll
  for (int i = 0; i < 4; ++i) acc[i] = make_float4(0.f, 0.f, 0.f, 0.f);
#pragma unroll 4
  for (int kq = 0; kq < 32; ++kq) {
    float4 xv[4], wv[4];
#pragma unroll
    for (int i = 0; i < 4; ++i) {
      int r = r4 + i;
      int slot = r * 32 + (kq ^ ((r >> 2) & 3));
      xv[i] = *(const float4*)&xs[slot * 4];
    }
#pragma unroll
    for (int q = 0; q < 4; ++q) wv[q] = *(const float4*)&Ws[(kq * 4 + q) * 64 + c4];
#pragma unroll
    for (int i = 0; i < 4; ++i) {
      fma4(acc[i], xv[i].x, wv[0]);
      fma4(acc[i], xv[i].y, wv[1]);
      fma4(acc[i], xv[i].z, wv[2]);
      fma4(acc[i], xv[i].w, wv[3]);
    }
  }
#pragma unroll
  for (int i = 0; i < 4; ++i) {
    int row = row0 + r4 + i;
    if (row < n) {
      float dv = dinv[row];
      uint2 pv;
      pv.x = pack_bf16(dv * acc[i].x, dv * acc[i].y);
      pv.y = pack_bf16(dv * acc[i].z, dv * acc[i].w);
      ((uint2*)h1)[(size_t)row * 16 + (threadIdx.x & 15)] = pv;
    }
  }
}

// ---------- aggregation ----------
// h4 rows are dinv-prefolded: h'[s] = dinv[s]*h[s].
// acc = h'[node] + sum_{e:dst=node} h'[src];  result_feat = dinv[node]*acc.
// EPI=1: out = bf16( dinv[node] * tanh(result + bias) )   (fold for next layer)
// EPI=0: out = bf16( result )
template <int EPI>
__global__ __launch_bounds__(256) void agg_kernel(const uint4* __restrict__ h4,
    const int* __restrict__ off, const int* __restrict__ csr,
    const float* __restrict__ dinv, const float* __restrict__ bias,
    unsigned int* __restrict__ out, int n) {
  int node = blockIdx.x * 4 + (threadIdx.x >> 6);
  if (node >= n) return;
  int lane = threadIdx.x & 63;
  int j = lane >> 3;   // edge slot 0..7
  int l = lane & 7;    // feature group (8 bf16 = 16B)
  float acc[8];
#pragma unroll
  for (int i = 0; i < 8; ++i) acc[i] = 0.f;
  if (j == 0) add8(acc, h4[(size_t)node * 8 + l]);  // self loop
  int e1 = off[node + 1];
  for (int ee = off[node] + j; ee < e1; ee += 8) {
    int s = csr[ee];
    add8(acc, h4[(size_t)s * 8 + l]);
  }
#pragma unroll
  for (int m = 8; m < 64; m <<= 1) {
#pragma unroll
    for (int i = 0; i < 8; ++i) acc[i] += __shfl_xor(acc[i], m);
  }
  if (j == 0) {
    float di = dinv[node];
    uint4 pv;
    if (EPI) {
      float4 b0 = ((const float4*)bias)[l * 2];
      float4 b1 = ((const float4*)bias)[l * 2 + 1];
      float v0 = di * tanhf(fmaf(di, acc[0], b0.x));
      float v1 = di * tanhf(fmaf(di, acc[1], b0.y));
      float v2 = di * tanhf(fmaf(di, acc[2], b0.z));
      float v3 = di * tanhf(fmaf(di, acc[3], b0.w));
      float v4 = di * tanhf(fmaf(di, acc[4], b1.x));
      float v5 = di * tanhf(fmaf(di, acc[5], b1.y));
      float v6 = di * tanhf(fmaf(di, acc[6], b1.z));
      float v7 = di * tanhf(fmaf(di, acc[7], b1.w));
      pv.x = pack_bf16(v0, v1); pv.y = pack_bf16(v2, v3);
      pv.z = pack_bf16(v4, v5); pv.w = pack_bf16(v6, v7);
    } else {
      pv.x = pack_bf16(di * acc[0], di * acc[1]);
      pv.y = pack_bf16(di * acc[2], di * acc[3]);
      pv.z = pack_bf16(di * acc[4], di * acc[5]);
      pv.w = pack_bf16(di * acc[6], di * acc[7]);
    }
    ((uint4*)out)[(size_t)node * 8 + l] = pv;
  }
}

// ---------- final: mean/logvar GEMMs + reparam ----------
// agg: [n][64] bf16; Wm,Wv: [64][32]; tile 64 rows x 32 cols.
__global__ __launch_bounds__(256) void final_kernel(const unsigned int* __restrict__ aggb,
    const float* __restrict__ Wm, const float* __restrict__ bm,
    const float* __restrict__ Wv, const float* __restrict__ bv,
    const float* __restrict__ noise, float* __restrict__ outZ,
    float* __restrict__ outM, float* __restrict__ outLv, int n) {
  __shared__ float WmS[64 * 32];
  __shared__ float WvS[64 * 32];
  __shared__ float aggS[64 * 68];  // stride 68 breaks bank conflicts
  for (int i = threadIdx.x; i < 64 * 8; i += 256) {
    ((float4*)WmS)[i] = ((const float4*)Wm)[i];
    ((float4*)WvS)[i] = ((const float4*)Wv)[i];
  }
  int row0 = blockIdx.x * 64;
  int nrow = n - row0; if (nrow > 64) nrow = 64;
  for (int i = threadIdx.x; i < 64 * 16; i += 256) {
    int r = i >> 4, g = i & 15;
    uint2 u = make_uint2(0u, 0u);
    if (r < nrow) u = ((const uint2*)aggb)[(size_t)(row0 + r) * 16 + g];
    float* d = &aggS[r * 68 + g * 4];
    d[0] = __uint_as_float(u.x << 16);
    d[1] = __uint_as_float(u.x & 0xFFFF0000u);
    d[2] = __uint_as_float(u.y << 16);
    d[3] = __uint_as_float(u.y & 0xFFFF0000u);
  }
  __syncthreads();
  int c4 = (threadIdx.x & 7) * 4;
  int r2 = (threadIdx.x >> 3) * 2;
  float4 am[2], av[2];
#pragma unroll
  for (int i = 0; i < 2; ++i) {
    am[i] = make_float4(0.f, 0.f, 0.f, 0.f);
    av[i] = make_float4(0.f, 0.f, 0.f, 0.f);
  }
#pragma unroll 4
  for (int kq = 0; kq < 16; ++kq) {
    float4 xa[2], wm[4], wv[4];
#pragma unroll
    for (int i = 0; i < 2; ++i) xa[i] = *(const float4*)&aggS[(r2 + i) * 68 + kq * 4];
#pragma unroll
    for (int q = 0; q < 4; ++q) {
      wm[q] = *(const float4*)&WmS[(kq * 4 + q) * 32 + c4];
      wv[q] = *(const float4*)&WvS[(kq * 4 + q) * 32 + c4];
    }
#pragma unroll
    for (int i = 0; i < 2; ++i) {
      fma4(am[i], xa[i].x, wm[0]); fma4(am[i], xa[i].y, wm[1]);
      fma4(am[i], xa[i].z, wm[2]); fma4(am[i], xa[i].w, wm[3]);
      fma4(av[i], xa[i].x, wv[0]); fma4(av[i], xa[i].y, wv[1]);
      fma4(av[i], xa[i].z, wv[2]); fma4(av[i], xa[i].w, wv[3]);
    }
  }
  float4 bmv = *(const float4*)&bm[c4];
  float4 bvv = *(const float4*)&bv[c4];
#pragma unroll
  for (int i = 0; i < 2; ++i) {
    int row = row0 + r2 + i;
    if (row < n) {
      float4 m = am[i]; m.x += bmv.x; m.y += bmv.y; m.z += bmv.z; m.w += bmv.w;
      float4 v = av[i]; v.x += bvv.x; v.y += bvv.y; v.z += bvv.z; v.w += bvv.w;
      size_t oi = (size_t)row * 8 + (threadIdx.x & 7);
      float4 nz = ((const float4*)noise)[oi];
      float4 z;
      z.x = fmaf(nz.x, expf(0.5f * v.x), m.x);
      z.y = fmaf(nz.y, expf(0.5f * v.y), m.y);
      z.z = fmaf(nz.z, expf(0.5f * v.z), m.z);
      z.w = fmaf(nz.w, expf(0.5f * v.w), m.w);
      ((float4*)outZ)[oi] = z;
      ((float4*)outM)[oi] = m;
      ((float4*)outLv)[oi] = v;
    }
  }
}

// ---------- launch ----------

extern "C" void kernel_launch(void* const* d_in, const int* in_sizes, int n_in,
                              void* d_out, int out_size, void* d_ws, size_t ws_size,
                              hipStream_t stream) {
  const float* x     = (const float*)d_in[0];
  const int*   edge  = (const int*)d_in[1];
  const float* W1    = (const float*)d_in[2];
  const float* b1    = (const float*)d_in[3];
  const float* Wm    = (const float*)d_in[4];
  const float* bm    = (const float*)d_in[5];
  const float* Wv    = (const float*)d_in[6];
  const float* bv    = (const float*)d_in[7];
  const float* noise = (const float*)d_in[8];
  int n = in_sizes[0] / 128;
  int e = in_sizes[1] / 2;
  const int* src = edge;
  const int* dst = edge + e;
  int nb = (n + 63) >> 6;   // 1563 buckets of 64 nodes

  // workspace layout (int units, 16B-aligned segments)
  int* bcnt = (int*)d_ws;                          // nb*16 (padded: 1 per 64B line)
  int* bcur = bcnt + nb * 16;                      // nb*16
  int* boff = bcur + nb * 16;                      // nb+1 (+pad)
  int* off  = boff + ((nb + 4) & ~3);              // n+1 (+pad)
  float* dinv = (float*)(off + ((n + 4) & ~3));    // n
  unsigned int* packed = (unsigned int*)(dinv + ((n + 3) & ~3)); // e
  int* csr  = (int*)(packed + ((e + 3) & ~3));     // e
  unsigned int* h1b = (unsigned int*)(csr + ((e + 3) & ~3)); // n*32 (bf16 h1')
  unsigned int* hb  = h1b + (size_t)n * 32;                  // n*32 (bf16 h')
  unsigned int* aggb = hb + (size_t)n * 32;                  // n*32 (bf16 agg2)

  float* outZ  = (float*)d_out;
  float* outM  = outZ + (size_t)n * 32;
  float* outLv = outM + (size_t)n * 32;

  const int nchunks = 128;  // partition grid = 8 groups x 128 chunks

  zero_kernel<<<(nb * 16 + 255) / 256, 256, 0, stream>>>(bcnt, nb * 16);
  bucket_hist_kernel<<<128, 256, 0, stream>>>(dst, bcnt, e, nb);
  bucket_scan_kernel<<<1, 256, 0, stream>>>(bcnt, boff, bcur, off, nb, n, e);
  partition_kernel<<<8 * nchunks, 256, 0, stream>>>(src, dst, bcur, packed, e, nchunks);
  csr_build_kernel<<<nb, 64, 0, stream>>>(packed, boff, off, dinv, csr, n);
  gemm1_kernel<<<(n + 63) / 64, 256, 0, stream>>>(x, W1, dinv, h1b, n);
  agg_kernel<1><<<(n + 3) / 4, 256, 0, stream>>>((const uint4*)h1b, off, csr, dinv, b1, hb, n);
  agg_kernel<0><<<(n + 3) / 4, 256, 0, stream>>>((const uint4*)hb, off, csr, dinv, b1, aggb, n);
  final_kernel<<<(n + 63) / 64, 256, 0, stream>>>(aggb, Wm, bm, Wv, bv, noise, outZ, outM, outLv, n);
}

// Round 5
// 223.758 us; speedup vs baseline: 2.2943x; 1.1555x over previous
//
#include <hip/hip_runtime.h>
#include <math.h>

#define TILE 4096          // edges per partition tile
#define CSHIFT 11          // coarse bucket = dst >> 11  (2048 nodes)
#define CMASK 2047
#define NCMAX 64

// ---------- helpers ----------

__device__ __forceinline__ unsigned int pack_bf16(float a, float b) {
  unsigned int ua = __float_as_uint(a);
  ua += 0x7FFFu + ((ua >> 16) & 1u);
  unsigned int ub = __float_as_uint(b);
  ub += 0x7FFFu + ((ub >> 16) & 1u);
  return (ua >> 16) | (ub & 0xFFFF0000u);
}

// acc[0..7] += bf16x8(hv)
__device__ __forceinline__ void add8(float* acc, uint4 hv) {
  unsigned int u[4] = {hv.x, hv.y, hv.z, hv.w};
#pragma unroll
  for (int i = 0; i < 4; ++i) {
    acc[2 * i]     += __uint_as_float(u[i] << 16);
    acc[2 * i + 1] += __uint_as_float(u[i] & 0xFFFF0000u);
  }
}

__device__ __forceinline__ void fma4(float4& acc, float s, const float4& w) {
  acc.x = fmaf(s, w.x, acc.x);
  acc.y = fmaf(s, w.y, acc.y);
  acc.z = fmaf(s, w.z, acc.z);
  acc.w = fmaf(s, w.w, acc.w);
}

// ---------- CSR build: two-level LDS-staged split ----------

__global__ void zero_kernel(int* __restrict__ p, int n) {
  int i = blockIdx.x * blockDim.x + threadIdx.x;
  if (i < n) p[i] = 0;
}

__global__ __launch_bounds__(256) void coarse_hist_kernel(const int* __restrict__ dst,
    int* __restrict__ ccnt, int e) {
  __shared__ int h[NCMAX];
  if (threadIdx.x < NCMAX) h[threadIdx.x] = 0;
  __syncthreads();
  for (int i = blockIdx.x * 256 + threadIdx.x; i < e; i += gridDim.x * 256)
    atomicAdd(&h[dst[i] >> CSHIFT], 1);
  __syncthreads();
  if (threadIdx.x < NCMAX && h[threadIdx.x])
    atomicAdd(&ccnt[threadIdx.x * 16], h[threadIdx.x]);
}

// single wave: exclusive scan of nc coarse counts; init cursors; off[n]=e
__global__ __launch_bounds__(64) void coarse_scan_kernel(const int* __restrict__ ccnt,
    int* __restrict__ coff, int* __restrict__ ccur, int* __restrict__ off,
    int nc, int n, int e) {
  int t = threadIdx.x;
  int v = (t < nc) ? ccnt[t * 16] : 0;
  int incl = v;
#pragma unroll
  for (int ofs = 1; ofs < 64; ofs <<= 1) {
    int w = __shfl_up(incl, ofs);
    if (t >= ofs) incl += w;
  }
  int excl = incl - v;
  if (t < nc) { coff[t] = excl; ccur[t * 16] = excl; }
  if (t == nc - 1) coff[nc] = incl;
  if (t == 0) off[n] = e;
}

// LDS-staged partition: sort a 4096-edge tile by coarse bucket in LDS, reserve
// a global range per bucket with ONE atomic, stream out contiguous segments
// (avg 84 edges = 336B per segment -> near-full-line writes, single writer).
__global__ __launch_bounds__(256) void coarse_partition_kernel(const int* __restrict__ src,
    const int* __restrict__ dst, int* __restrict__ ccur,
    unsigned int* __restrict__ packed, int e) {
  __shared__ unsigned int stage[TILE];
  __shared__ unsigned char bid[TILE];
  __shared__ int hist[NCMAX], excl[NCMAX], gbase[NCMAX], lcur[NCMAX];
  int ntiles = (e + TILE - 1) / TILE;
  for (int tile = blockIdx.x; tile < ntiles; tile += gridDim.x) {
    int i0 = tile * TILE;
    int cnt = e - i0; if (cnt > TILE) cnt = TILE;
    if (threadIdx.x < NCMAX) hist[threadIdx.x] = 0;
    __syncthreads();
    int myS[16], myD[16];
#pragma unroll
    for (int k = 0; k < 16; ++k) {
      int li = threadIdx.x + k * 256;
      if (li < cnt) {
        myS[k] = src[i0 + li];
        myD[k] = dst[i0 + li];
        atomicAdd(&hist[myD[k] >> CSHIFT], 1);
      }
    }
    __syncthreads();
    if (threadIdx.x < NCMAX) {  // wave 0: scan 64 buckets
      int t = threadIdx.x;
      int v = hist[t];
      int incl = v;
#pragma unroll
      for (int ofs = 1; ofs < 64; ofs <<= 1) {
        int w = __shfl_up(incl, ofs);
        if (t >= ofs) incl += w;
      }
      excl[t] = incl - v;
      lcur[t] = incl - v;
    }
    __syncthreads();
#pragma unroll
    for (int k = 0; k < 16; ++k) {
      int li = threadIdx.x + k * 256;
      if (li < cnt) {
        int c = myD[k] >> CSHIFT;
        int p = atomicAdd(&lcur[c], 1);
        stage[p] = (unsigned int)myS[k] | ((unsigned int)(myD[k] & CMASK) << 17);
        bid[p] = (unsigned char)c;
      }
    }
    __syncthreads();
    if (threadIdx.x < NCMAX) {
      int t = threadIdx.x;
      int cc = lcur[t] - excl[t];
      gbase[t] = cc ? atomicAdd(&ccur[t * 16], cc) : 0;
    }
    __syncthreads();
    for (int i = threadIdx.x; i < cnt; i += 256) {
      int c = bid[i];
      packed[gbase[c] + (i - excl[c])] = stage[i];
    }
    __syncthreads();  // protect hist/stage reuse
  }
}

// one block per coarse bucket: counting sort 2048 node sub-buckets -> csr, off, dinv.
// All scattered writes confined to this block's ~100KB region (one XCD's L2).
__global__ __launch_bounds__(512) void csr_fine_kernel(const unsigned int* __restrict__ packed,
    const int* __restrict__ coff, int* __restrict__ off, float* __restrict__ dinv,
    int* __restrict__ csr, int n) {
  __shared__ int lh[2048];
  __shared__ int lsum[512];
  int b = blockIdx.x;
  int t = threadIdx.x;
  int e0 = coff[b], e1 = coff[b + 1];
  int node0 = b << CSHIFT;
  for (int i = t; i < 2048; i += 512) lh[i] = 0;
  __syncthreads();
  for (int i = e0 + t; i < e1; i += 512) atomicAdd(&lh[packed[i] >> 17], 1);
  __syncthreads();
  int base = t * 4;
  int v0 = lh[base], v1 = lh[base + 1], v2 = lh[base + 2], v3 = lh[base + 3];
  int tsum = v0 + v1 + v2 + v3;
  lsum[t] = tsum;
  __syncthreads();
  for (int ofs = 1; ofs < 512; ofs <<= 1) {
    int add = (t >= ofs) ? lsum[t - ofs] : 0;
    __syncthreads();
    lsum[t] += add;
    __syncthreads();
  }
  int ex = lsum[t] - tsum;
  int exc0 = ex, exc1 = ex + v0, exc2 = ex + v0 + v1, exc3 = ex + v0 + v1 + v2;
  lh[base] = exc0; lh[base + 1] = exc1; lh[base + 2] = exc2; lh[base + 3] = exc3;
  int node = node0 + base;
  if (node < n)     { off[node]     = e0 + exc0; dinv[node]     = rsqrtf((float)(v0 + 1)); }
  if (node + 1 < n) { off[node + 1] = e0 + exc1; dinv[node + 1] = rsqrtf((float)(v1 + 1)); }
  if (node + 2 < n) { off[node + 2] = e0 + exc2; dinv[node + 2] = rsqrtf((float)(v2 + 1)); }
  if (node + 3 < n) { off[node + 3] = e0 + exc3; dinv[node + 3] = rsqrtf((float)(v3 + 1)); }
  __syncthreads();
  for (int i = e0 + t; i < e1; i += 512) {
    unsigned int p = packed[i];
    int nl = p >> 17;
    int pos = atomicAdd(&lh[nl], 1);
    csr[e0 + pos] = (int)(p & 0x1FFFFu);
  }
}

// ---------- h1' = dinv * (x @ W1), output bf16 ----------
__global__ __launch_bounds__(256) void gemm1_kernel(const float* __restrict__ x,
    const float* __restrict__ W1, const float* __restrict__ dinv,
    unsigned int* __restrict__ h1, int n) {
  __shared__ float Ws[128 * 64];        // 32 KB
  __shared__ float xs[64 * 128];        // 32 KB, float4-slot XOR swizzle
  for (int i = threadIdx.x; i < 128 * 16; i += 256)
    ((float4*)Ws)[i] = ((const float4*)W1)[i];
  int row0 = blockIdx.x * 64;
  int nrow = n - row0; if (nrow > 64) nrow = 64;
  for (int i = threadIdx.x; i < 64 * 32; i += 256) {
    int r = i >> 5, kq = i & 31;
    float4 v = make_float4(0.f, 0.f, 0.f, 0.f);
    if (r < nrow) v = ((const float4*)(x + (size_t)(row0 + r) * 128))[kq];
    int slot = r * 32 + (kq ^ ((r >> 2) & 3));
    *(float4*)&xs[slot * 4] = v;
  }
  __syncthreads();
  int c4 = (threadIdx.x & 15) * 4;
  int r4 = (threadIdx.x >> 4) * 4;
  float4 acc[4];
#pragma unroll
  for (int i = 0; i < 4; ++i) acc[i] = make_float4(0.f, 0.f, 0.f, 0.f);
#pragma unroll 4
  for (int kq = 0; kq < 32; ++kq) {
    float4 xv[4], wv[4];
#pragma unroll
    for (int i = 0; i < 4; ++i) {
      int r = r4 + i;
      int slot = r * 32 + (kq ^ ((r >> 2) & 3));
      xv[i] = *(const float4*)&xs[slot * 4];
    }
#pragma unroll
    for (int q = 0; q < 4; ++q) wv[q] = *(const float4*)&Ws[(kq * 4 + q) * 64 + c4];
#pragma unroll
    for (int i = 0; i < 4; ++i) {
      fma4(acc[i], xv[i].x, wv[0]);
      fma4(acc[i], xv[i].y, wv[1]);
      fma4(acc[i], xv[i].z, wv[2]);
      fma4(acc[i], xv[i].w, wv[3]);
    }
  }
#pragma unroll
  for (int i = 0; i < 4; ++i) {
    int row = row0 + r4 + i;
    if (row < n) {
      float dv = dinv[row];
      uint2 pv;
      pv.x = pack_bf16(dv * acc[i].x, dv * acc[i].y);
      pv.y = pack_bf16(dv * acc[i].z, dv * acc[i].w);
      ((uint2*)h1)[(size_t)row * 16 + (threadIdx.x & 15)] = pv;
    }
  }
}

// ---------- aggregation ----------
// h4 rows are dinv-prefolded: h'[s] = dinv[s]*h[s].
// acc = h'[node] + sum_{e:dst=node} h'[src];  result_feat = dinv[node]*acc.
// EPI=1: out = bf16( dinv[node] * tanh(result + bias) )   (fold for next layer)
// EPI=0: out = bf16( result )
template <int EPI>
__global__ __launch_bounds__(256) void agg_kernel(const uint4* __restrict__ h4,
    const int* __restrict__ off, const int* __restrict__ csr,
    const float* __restrict__ dinv, const float* __restrict__ bias,
    unsigned int* __restrict__ out, int n) {
  int node = blockIdx.x * 4 + (threadIdx.x >> 6);
  if (node >= n) return;
  int lane = threadIdx.x & 63;
  int j = lane >> 3;   // edge slot 0..7
  int l = lane & 7;    // feature group (8 bf16 = 16B)
  float acc[8];
#pragma unroll
  for (int i = 0; i < 8; ++i) acc[i] = 0.f;
  if (j == 0) add8(acc, h4[(size_t)node * 8 + l]);  // self loop
  int e1 = off[node + 1];
  for (int ee = off[node] + j; ee < e1; ee += 8) {
    int s = csr[ee];
    add8(acc, h4[(size_t)s * 8 + l]);
  }
#pragma unroll
  for (int m = 8; m < 64; m <<= 1) {
#pragma unroll
    for (int i = 0; i < 8; ++i) acc[i] += __shfl_xor(acc[i], m);
  }
  if (j == 0) {
    float di = dinv[node];
    uint4 pv;
    if (EPI) {
      float4 b0 = ((const float4*)bias)[l * 2];
      float4 b1 = ((const float4*)bias)[l * 2 + 1];
      float v0 = di * tanhf(fmaf(di, acc[0], b0.x));
      float v1 = di * tanhf(fmaf(di, acc[1], b0.y));
      float v2 = di * tanhf(fmaf(di, acc[2], b0.z));
      float v3 = di * tanhf(fmaf(di, acc[3], b0.w));
      float v4 = di * tanhf(fmaf(di, acc[4], b1.x));
      float v5 = di * tanhf(fmaf(di, acc[5], b1.y));
      float v6 = di * tanhf(fmaf(di, acc[6], b1.z));
      float v7 = di * tanhf(fmaf(di, acc[7], b1.w));
      pv.x = pack_bf16(v0, v1); pv.y = pack_bf16(v2, v3);
      pv.z = pack_bf16(v4, v5); pv.w = pack_bf16(v6, v7);
    } else {
      pv.x = pack_bf16(di * acc[0], di * acc[1]);
      pv.y = pack_bf16(di * acc[2], di * acc[3]);
      pv.z = pack_bf16(di * acc[4], di * acc[5]);
      pv.w = pack_bf16(di * acc[6], di * acc[7]);
    }
    ((uint4*)out)[(size_t)node * 8 + l] = pv;
  }
}

// ---------- final: mean/logvar GEMMs + reparam ----------
__global__ __launch_bounds__(256) void final_kernel(const unsigned int* __restrict__ aggb,
    const float* __restrict__ Wm, const float* __restrict__ bm,
    const float* __restrict__ Wv, const float* __restrict__ bv,
    const float* __restrict__ noise, float* __restrict__ outZ,
    float* __restrict__ outM, float* __restrict__ outLv, int n) {
  __shared__ float WmS[64 * 32];
  __shared__ float WvS[64 * 32];
  __shared__ float aggS[64 * 68];  // stride 68 breaks bank conflicts
  for (int i = threadIdx.x; i < 64 * 8; i += 256) {
    ((float4*)WmS)[i] = ((const float4*)Wm)[i];
    ((float4*)WvS)[i] = ((const float4*)Wv)[i];
  }
  int row0 = blockIdx.x * 64;
  int nrow = n - row0; if (nrow > 64) nrow = 64;
  for (int i = threadIdx.x; i < 64 * 16; i += 256) {
    int r = i >> 4, g = i & 15;
    uint2 u = make_uint2(0u, 0u);
    if (r < nrow) u = ((const uint2*)aggb)[(size_t)(row0 + r) * 16 + g];
    float* d = &aggS[r * 68 + g * 4];
    d[0] = __uint_as_float(u.x << 16);
    d[1] = __uint_as_float(u.x & 0xFFFF0000u);
    d[2] = __uint_as_float(u.y << 16);
    d[3] = __uint_as_float(u.y & 0xFFFF0000u);
  }
  __syncthreads();
  int c4 = (threadIdx.x & 7) * 4;
  int r2 = (threadIdx.x >> 3) * 2;
  float4 am[2], av[2];
#pragma unroll
  for (int i = 0; i < 2; ++i) {
    am[i] = make_float4(0.f, 0.f, 0.f, 0.f);
    av[i] = make_float4(0.f, 0.f, 0.f, 0.f);
  }
#pragma unroll 4
  for (int kq = 0; kq < 16; ++kq) {
    float4 xa[2], wm[4], wv[4];
#pragma unroll
    for (int i = 0; i < 2; ++i) xa[i] = *(const float4*)&aggS[(r2 + i) * 68 + kq * 4];
#pragma unroll
    for (int q = 0; q < 4; ++q) {
      wm[q] = *(const float4*)&WmS[(kq * 4 + q) * 32 + c4];
      wv[q] = *(const float4*)&WvS[(kq * 4 + q) * 32 + c4];
    }
#pragma unroll
    for (int i = 0; i < 2; ++i) {
      fma4(am[i], xa[i].x, wm[0]); fma4(am[i], xa[i].y, wm[1]);
      fma4(am[i], xa[i].z, wm[2]); fma4(am[i], xa[i].w, wm[3]);
      fma4(av[i], xa[i].x, wv[0]); fma4(av[i], xa[i].y, wv[1]);
      fma4(av[i], xa[i].z, wv[2]); fma4(av[i], xa[i].w, wv[3]);
    }
  }
  float4 bmv = *(const float4*)&bm[c4];
  float4 bvv = *(const float4*)&bv[c4];
#pragma unroll
  for (int i = 0; i < 2; ++i) {
    int row = row0 + r2 + i;
    if (row < n) {
      float4 m = am[i]; m.x += bmv.x; m.y += bmv.y; m.z += bmv.z; m.w += bmv.w;
      float4 v = av[i]; v.x += bvv.x; v.y += bvv.y; v.z += bvv.z; v.w += bvv.w;
      size_t oi = (size_t)row * 8 + (threadIdx.x & 7);
      float4 nz = ((const float4*)noise)[oi];
      float4 z;
      z.x = fmaf(nz.x, expf(0.5f * v.x), m.x);
      z.y = fmaf(nz.y, expf(0.5f * v.y), m.y);
      z.z = fmaf(nz.z, expf(0.5f * v.z), m.z);
      z.w = fmaf(nz.w, expf(0.5f * v.w), m.w);
      ((float4*)outZ)[oi] = z;
      ((float4*)outM)[oi] = m;
      ((float4*)outLv)[oi] = v;
    }
  }
}

// ---------- launch ----------

extern "C" void kernel_launch(void* const* d_in, const int* in_sizes, int n_in,
                              void* d_out, int out_size, void* d_ws, size_t ws_size,
                              hipStream_t stream) {
  const float* x     = (const float*)d_in[0];
  const int*   edge  = (const int*)d_in[1];
  const float* W1    = (const float*)d_in[2];
  const float* b1    = (const float*)d_in[3];
  const float* Wm    = (const float*)d_in[4];
  const float* bm    = (const float*)d_in[5];
  const float* Wv    = (const float*)d_in[6];
  const float* bv    = (const float*)d_in[7];
  const float* noise = (const float*)d_in[8];
  int n = in_sizes[0] / 128;
  int e = in_sizes[1] / 2;
  const int* src = edge;
  const int* dst = edge + e;
  int nc = (n + CMASK) >> CSHIFT;   // 49 coarse buckets of 2048 nodes

  // workspace layout (int units, 16B-aligned segments)
  int* ccnt = (int*)d_ws;                          // NCMAX*16 (1 per 64B line)
  int* ccur = ccnt + NCMAX * 16;                   // NCMAX*16
  int* coff = ccur + NCMAX * 16;                   // NCMAX+1 (+pad)
  int* off  = coff + (NCMAX + 4);                  // n+1 (+pad)
  float* dinv = (float*)(off + ((n + 4) & ~3));    // n
  unsigned int* packed = (unsigned int*)(dinv + ((n + 3) & ~3)); // e
  int* csr  = (int*)(packed + ((e + 3) & ~3));     // e
  unsigned int* h1b = (unsigned int*)(csr + ((e + 3) & ~3)); // n*32 (bf16 h1')
  unsigned int* hb  = h1b + (size_t)n * 32;                  // n*32 (bf16 h')
  unsigned int* aggb = hb + (size_t)n * 32;                  // n*32 (bf16 agg2)

  float* outZ  = (float*)d_out;
  float* outM  = outZ + (size_t)n * 32;
  float* outLv = outM + (size_t)n * 32;

  int ntiles = (e + TILE - 1) / TILE;

  zero_kernel<<<(NCMAX * 16 + 255) / 256, 256, 0, stream>>>(ccnt, NCMAX * 16);
  coarse_hist_kernel<<<256, 256, 0, stream>>>(dst, ccnt, e);
  coarse_scan_kernel<<<1, 64, 0, stream>>>(ccnt, coff, ccur, off, nc, n, e);
  coarse_partition_kernel<<<ntiles, 256, 0, stream>>>(src, dst, ccur, packed, e);
  csr_fine_kernel<<<nc, 512, 0, stream>>>(packed, coff, off, dinv, csr, n);
  gemm1_kernel<<<(n + 63) / 64, 256, 0, stream>>>(x, W1, dinv, h1b, n);
  agg_kernel<1><<<(n + 3) / 4, 256, 0, stream>>>((const uint4*)h1b, off, csr, dinv, b1, hb, n);
  agg_kernel<0><<<(n + 3) / 4, 256, 0, stream>>>((const uint4*)hb, off, csr, dinv, b1, aggb, n);
  final_kernel<<<(n + 63) / 64, 256, 0, stream>>>(aggb, Wm, bm, Wv, bv, noise, outZ, outM, outLv, n);
}

// Round 6
// 217.085 us; speedup vs baseline: 2.3648x; 1.0307x over previous
//
#include <hip/hip_runtime.h>
#include <math.h>

#define TILE 4096          // edges per partition tile
#define CSHIFT 11          // coarse bucket = dst >> 11  (2048 nodes)
#define CMASK 2047
#define NCMAX 64

// ---------- helpers ----------

__device__ __forceinline__ unsigned int pack_bf16(float a, float b) {
  unsigned int ua = __float_as_uint(a);
  ua += 0x7FFFu + ((ua >> 16) & 1u);
  unsigned int ub = __float_as_uint(b);
  ub += 0x7FFFu + ((ub >> 16) & 1u);
  return (ua >> 16) | (ub & 0xFFFF0000u);
}

// acc[0..7] += bf16x8(hv)
__device__ __forceinline__ void add8(float* acc, uint4 hv) {
  unsigned int u[4] = {hv.x, hv.y, hv.z, hv.w};
#pragma unroll
  for (int i = 0; i < 4; ++i) {
    acc[2 * i]     += __uint_as_float(u[i] << 16);
    acc[2 * i + 1] += __uint_as_float(u[i] & 0xFFFF0000u);
  }
}

__device__ __forceinline__ void fma4(float4& acc, float s, const float4& w) {
  acc.x = fmaf(s, w.x, acc.x);
  acc.y = fmaf(s, w.y, acc.y);
  acc.z = fmaf(s, w.z, acc.z);
  acc.w = fmaf(s, w.w, acc.w);
}

// ---------- CSR build: two-level LDS-staged split ----------

__global__ void zero_kernel(int* __restrict__ p, int n) {
  int i = blockIdx.x * blockDim.x + threadIdx.x;
  if (i < n) p[i] = 0;
}

__global__ __launch_bounds__(256) void coarse_hist_kernel(const int* __restrict__ dst,
    int* __restrict__ ccnt, int e) {
  __shared__ int h[NCMAX];
  if (threadIdx.x < NCMAX) h[threadIdx.x] = 0;
  __syncthreads();
  for (int i = blockIdx.x * 256 + threadIdx.x; i < e; i += gridDim.x * 256)
    atomicAdd(&h[dst[i] >> CSHIFT], 1);
  __syncthreads();
  if (threadIdx.x < NCMAX && h[threadIdx.x])
    atomicAdd(&ccnt[threadIdx.x * 16], h[threadIdx.x]);
}

// single wave: exclusive scan of nc coarse counts; init cursors; off[n]=e
__global__ __launch_bounds__(64) void coarse_scan_kernel(const int* __restrict__ ccnt,
    int* __restrict__ coff, int* __restrict__ ccur, int* __restrict__ off,
    int nc, int n, int e) {
  int t = threadIdx.x;
  int v = (t < nc) ? ccnt[t * 16] : 0;
  int incl = v;
#pragma unroll
  for (int ofs = 1; ofs < 64; ofs <<= 1) {
    int w = __shfl_up(incl, ofs);
    if (t >= ofs) incl += w;
  }
  int excl = incl - v;
  if (t < nc) { coff[t] = excl; ccur[t * 16] = excl; }
  if (t == nc - 1) coff[nc] = incl;
  if (t == 0) off[n] = e;
}

// LDS-staged partition: sort a 4096-edge tile by coarse bucket in LDS, reserve
// a global range per bucket with ONE atomic, stream out contiguous segments.
__global__ __launch_bounds__(256) void coarse_partition_kernel(const int* __restrict__ src,
    const int* __restrict__ dst, int* __restrict__ ccur,
    unsigned int* __restrict__ packed, int e) {
  __shared__ unsigned int stage[TILE];
  __shared__ unsigned char bid[TILE];
  __shared__ int hist[NCMAX], excl[NCMAX], gbase[NCMAX], lcur[NCMAX];
  int ntiles = (e + TILE - 1) / TILE;
  for (int tile = blockIdx.x; tile < ntiles; tile += gridDim.x) {
    int i0 = tile * TILE;
    int cnt = e - i0; if (cnt > TILE) cnt = TILE;
    if (threadIdx.x < NCMAX) hist[threadIdx.x] = 0;
    __syncthreads();
    int myS[16], myD[16];
#pragma unroll
    for (int k = 0; k < 16; ++k) {
      int li = threadIdx.x + k * 256;
      if (li < cnt) {
        myS[k] = src[i0 + li];
        myD[k] = dst[i0 + li];
        atomicAdd(&hist[myD[k] >> CSHIFT], 1);
      }
    }
    __syncthreads();
    if (threadIdx.x < NCMAX) {  // wave 0: scan 64 buckets
      int t = threadIdx.x;
      int v = hist[t];
      int incl = v;
#pragma unroll
      for (int ofs = 1; ofs < 64; ofs <<= 1) {
        int w = __shfl_up(incl, ofs);
        if (t >= ofs) incl += w;
      }
      excl[t] = incl - v;
      lcur[t] = incl - v;
    }
    __syncthreads();
#pragma unroll
    for (int k = 0; k < 16; ++k) {
      int li = threadIdx.x + k * 256;
      if (li < cnt) {
        int c = myD[k] >> CSHIFT;
        int p = atomicAdd(&lcur[c], 1);
        stage[p] = (unsigned int)myS[k] | ((unsigned int)(myD[k] & CMASK) << 17);
        bid[p] = (unsigned char)c;
      }
    }
    __syncthreads();
    if (threadIdx.x < NCMAX) {
      int t = threadIdx.x;
      int cc = lcur[t] - excl[t];
      gbase[t] = cc ? atomicAdd(&ccur[t * 16], cc) : 0;
    }
    __syncthreads();
    for (int i = threadIdx.x; i < cnt; i += 256) {
      int c = bid[i];
      packed[gbase[c] + (i - excl[c])] = stage[i];
    }
    __syncthreads();  // protect hist/stage reuse
  }
}

// one block per coarse bucket: counting sort 2048 node sub-buckets -> csr, off, dinv.
__global__ __launch_bounds__(512) void csr_fine_kernel(const unsigned int* __restrict__ packed,
    const int* __restrict__ coff, int* __restrict__ off, float* __restrict__ dinv,
    int* __restrict__ csr, int n) {
  __shared__ int lh[2048];
  __shared__ int lsum[512];
  int b = blockIdx.x;
  int t = threadIdx.x;
  int e0 = coff[b], e1 = coff[b + 1];
  int node0 = b << CSHIFT;
  for (int i = t; i < 2048; i += 512) lh[i] = 0;
  __syncthreads();
  for (int i = e0 + t; i < e1; i += 512) atomicAdd(&lh[packed[i] >> 17], 1);
  __syncthreads();
  int base = t * 4;
  int v0 = lh[base], v1 = lh[base + 1], v2 = lh[base + 2], v3 = lh[base + 3];
  int tsum = v0 + v1 + v2 + v3;
  lsum[t] = tsum;
  __syncthreads();
  for (int ofs = 1; ofs < 512; ofs <<= 1) {
    int add = (t >= ofs) ? lsum[t - ofs] : 0;
    __syncthreads();
    lsum[t] += add;
    __syncthreads();
  }
  int ex = lsum[t] - tsum;
  int exc0 = ex, exc1 = ex + v0, exc2 = ex + v0 + v1, exc3 = ex + v0 + v1 + v2;
  lh[base] = exc0; lh[base + 1] = exc1; lh[base + 2] = exc2; lh[base + 3] = exc3;
  int node = node0 + base;
  if (node < n)     { off[node]     = e0 + exc0; dinv[node]     = rsqrtf((float)(v0 + 1)); }
  if (node + 1 < n) { off[node + 1] = e0 + exc1; dinv[node + 1] = rsqrtf((float)(v1 + 1)); }
  if (node + 2 < n) { off[node + 2] = e0 + exc2; dinv[node + 2] = rsqrtf((float)(v2 + 1)); }
  if (node + 3 < n) { off[node + 3] = e0 + exc3; dinv[node + 3] = rsqrtf((float)(v3 + 1)); }
  __syncthreads();
  for (int i = e0 + t; i < e1; i += 512) {
    unsigned int p = packed[i];
    int nl = p >> 17;
    int pos = atomicAdd(&lh[nl], 1);
    csr[e0 + pos] = (int)(p & 0x1FFFFu);
  }
}

// ---------- h1' = dinv * (x @ W1), output bf16 ----------
__global__ __launch_bounds__(256) void gemm1_kernel(const float* __restrict__ x,
    const float* __restrict__ W1, const float* __restrict__ dinv,
    unsigned int* __restrict__ h1, int n) {
  __shared__ float Ws[128 * 64];        // 32 KB
  __shared__ float xs[64 * 128];        // 32 KB, float4-slot XOR swizzle
  for (int i = threadIdx.x; i < 128 * 16; i += 256)
    ((float4*)Ws)[i] = ((const float4*)W1)[i];
  int row0 = blockIdx.x * 64;
  int nrow = n - row0; if (nrow > 64) nrow = 64;
  for (int i = threadIdx.x; i < 64 * 32; i += 256) {
    int r = i >> 5, kq = i & 31;
    float4 v = make_float4(0.f, 0.f, 0.f, 0.f);
    if (r < nrow) v = ((const float4*)(x + (size_t)(row0 + r) * 128))[kq];
    int slot = r * 32 + (kq ^ ((r >> 2) & 3));
    *(float4*)&xs[slot * 4] = v;
  }
  __syncthreads();
  int c4 = (threadIdx.x & 15) * 4;
  int r4 = (threadIdx.x >> 4) * 4;
  float4 acc[4];
#pragma unroll
  for (int i = 0; i < 4; ++i) acc[i] = make_float4(0.f, 0.f, 0.f, 0.f);
#pragma unroll 4
  for (int kq = 0; kq < 32; ++kq) {
    float4 xv[4], wv[4];
#pragma unroll
    for (int i = 0; i < 4; ++i) {
      int r = r4 + i;
      int slot = r * 32 + (kq ^ ((r >> 2) & 3));
      xv[i] = *(const float4*)&xs[slot * 4];
    }
#pragma unroll
    for (int q = 0; q < 4; ++q) wv[q] = *(const float4*)&Ws[(kq * 4 + q) * 64 + c4];
#pragma unroll
    for (int i = 0; i < 4; ++i) {
      fma4(acc[i], xv[i].x, wv[0]);
      fma4(acc[i], xv[i].y, wv[1]);
      fma4(acc[i], xv[i].z, wv[2]);
      fma4(acc[i], xv[i].w, wv[3]);
    }
  }
#pragma unroll
  for (int i = 0; i < 4; ++i) {
    int row = row0 + r4 + i;
    if (row < n) {
      float dv = dinv[row];
      uint2 pv;
      pv.x = pack_bf16(dv * acc[i].x, dv * acc[i].y);
      pv.y = pack_bf16(dv * acc[i].z, dv * acc[i].w);
      ((uint2*)h1)[(size_t)row * 16 + (threadIdx.x & 15)] = pv;
    }
  }
}

// ---------- aggregation ----------
// 16 edge-slots x 4 feature-lanes per wave. h rows dinv-prefolded (h'=dinv*h).
// acc = h'[node] + sum_{e:dst=node} h'[src];  result = dinv[node]*acc.
// Recursive-halving shfl reduce leaves ONE feature per lane (static reg indices).
// EPI=1: out = bf16( dinv * tanh(result + bias) ); EPI=0: out = bf16(result).
template <int EPI>
__global__ __launch_bounds__(256) void agg_kernel(const uint4* __restrict__ h4,
    const int* __restrict__ off, const int* __restrict__ csr,
    const float* __restrict__ dinv, const float* __restrict__ bias,
    unsigned int* __restrict__ out, int n) {
  int node = blockIdx.x * 4 + (threadIdx.x >> 6);
  if (node >= n) return;
  int lane = threadIdx.x & 63;
  int j = lane >> 2;   // edge slot 0..15
  int l = lane & 3;    // feature quarter (16 bf16 = 32B = 2 uint4)
  float acc[16];
#pragma unroll
  for (int i = 0; i < 16; ++i) acc[i] = 0.f;
  if (j == 0) {  // self loop
    uint4 a = h4[(size_t)node * 8 + l * 2];
    uint4 b = h4[(size_t)node * 8 + l * 2 + 1];
    add8(acc, a);
    add8(acc + 8, b);
  }
  int e1 = off[node + 1];
  for (int ee = off[node] + j; ee < e1; ee += 16) {
    int s = __builtin_nontemporal_load(&csr[ee]);
    uint4 a = h4[(size_t)s * 8 + l * 2];
    uint4 b = h4[(size_t)s * 8 + l * 2 + 1];
    add8(acc, a);
    add8(acc + 8, b);
  }
  // recursive-halving reduce over the 16 slots; feature count 16 -> 1
#pragma unroll
  for (int i = 0; i < 8; ++i) {
    float tlo = acc[i]     + __shfl_xor(acc[i], 4);
    float thi = acc[i + 8] + __shfl_xor(acc[i + 8], 4);
    acc[i] = (j & 1) ? thi : tlo;
  }
#pragma unroll
  for (int i = 0; i < 4; ++i) {
    float tlo = acc[i]     + __shfl_xor(acc[i], 8);
    float thi = acc[i + 4] + __shfl_xor(acc[i + 4], 8);
    acc[i] = (j & 2) ? thi : tlo;
  }
#pragma unroll
  for (int i = 0; i < 2; ++i) {
    float tlo = acc[i]     + __shfl_xor(acc[i], 16);
    float thi = acc[i + 2] + __shfl_xor(acc[i + 2], 16);
    acc[i] = (j & 4) ? thi : tlo;
  }
  float a0, a1;
  a0 = acc[0] + __shfl_xor(acc[0], 32);
  a1 = acc[1] + __shfl_xor(acc[1], 32);
  float a = (j & 8) ? a1 : a0;
  // this lane now owns feature f = l*16 + j0*8 + j1*4 + j2*2 + j3
  int f = l * 16 + ((j & 1) << 3) + ((j & 2) << 1) + ((j >> 2) & 1) * 2 + ((j >> 3) & 1);
  float di = dinv[node];
  float val;
  if (EPI) {
    val = di * tanhf(fmaf(di, a, bias[f]));
  } else {
    val = di * a;
  }
  // pack feature pairs (f even with f+1, partner lane = lane^32) and store
  float pv = __shfl_xor(val, 32);
  if (!(j & 8)) {  // f even
    unsigned int w = pack_bf16(val, pv);
    int half = l * 8 + ((j & 1) << 2) + (j & 2) + ((j >> 2) & 1);  // f/2
    out[(size_t)node * 32 + half] = w;
  }
}

// ---------- final: mean/logvar GEMMs + reparam ----------
__global__ __launch_bounds__(256) void final_kernel(const unsigned int* __restrict__ aggb,
    const float* __restrict__ Wm, const float* __restrict__ bm,
    const float* __restrict__ Wv, const float* __restrict__ bv,
    const float* __restrict__ noise, float* __restrict__ outZ,
    float* __restrict__ outM, float* __restrict__ outLv, int n) {
  __shared__ float WmS[64 * 32];
  __shared__ float WvS[64 * 32];
  __shared__ float aggS[64 * 68];  // stride 68 breaks bank conflicts
  for (int i = threadIdx.x; i < 64 * 8; i += 256) {
    ((float4*)WmS)[i] = ((const float4*)Wm)[i];
    ((float4*)WvS)[i] = ((const float4*)Wv)[i];
  }
  int row0 = blockIdx.x * 64;
  int nrow = n - row0; if (nrow > 64) nrow = 64;
  for (int i = threadIdx.x; i < 64 * 16; i += 256) {
    int r = i >> 4, g = i & 15;
    uint2 u = make_uint2(0u, 0u);
    if (r < nrow) u = ((const uint2*)aggb)[(size_t)(row0 + r) * 16 + g];
    float* d = &aggS[r * 68 + g * 4];
    d[0] = __uint_as_float(u.x << 16);
    d[1] = __uint_as_float(u.x & 0xFFFF0000u);
    d[2] = __uint_as_float(u.y << 16);
    d[3] = __uint_as_float(u.y & 0xFFFF0000u);
  }
  __syncthreads();
  int c4 = (threadIdx.x & 7) * 4;
  int r2 = (threadIdx.x >> 3) * 2;
  float4 am[2], av[2];
#pragma unroll
  for (int i = 0; i < 2; ++i) {
    am[i] = make_float4(0.f, 0.f, 0.f, 0.f);
    av[i] = make_float4(0.f, 0.f, 0.f, 0.f);
  }
#pragma unroll 4
  for (int kq = 0; kq < 16; ++kq) {
    float4 xa[2], wm[4], wv[4];
#pragma unroll
    for (int i = 0; i < 2; ++i) xa[i] = *(const float4*)&aggS[(r2 + i) * 68 + kq * 4];
#pragma unroll
    for (int q = 0; q < 4; ++q) {
      wm[q] = *(const float4*)&WmS[(kq * 4 + q) * 32 + c4];
      wv[q] = *(const float4*)&WvS[(kq * 4 + q) * 32 + c4];
    }
#pragma unroll
    for (int i = 0; i < 2; ++i) {
      fma4(am[i], xa[i].x, wm[0]); fma4(am[i], xa[i].y, wm[1]);
      fma4(am[i], xa[i].z, wm[2]); fma4(am[i], xa[i].w, wm[3]);
      fma4(av[i], xa[i].x, wv[0]); fma4(av[i], xa[i].y, wv[1]);
      fma4(av[i], xa[i].z, wv[2]); fma4(av[i], xa[i].w, wv[3]);
    }
  }
  float4 bmv = *(const float4*)&bm[c4];
  float4 bvv = *(const float4*)&bv[c4];
#pragma unroll
  for (int i = 0; i < 2; ++i) {
    int row = row0 + r2 + i;
    if (row < n) {
      float4 m = am[i]; m.x += bmv.x; m.y += bmv.y; m.z += bmv.z; m.w += bmv.w;
      float4 v = av[i]; v.x += bvv.x; v.y += bvv.y; v.z += bvv.z; v.w += bvv.w;
      size_t oi = (size_t)row * 8 + (threadIdx.x & 7);
      float4 nz = ((const float4*)noise)[oi];
      float4 z;
      z.x = fmaf(nz.x, expf(0.5f * v.x), m.x);
      z.y = fmaf(nz.y, expf(0.5f * v.y), m.y);
      z.z = fmaf(nz.z, expf(0.5f * v.z), m.z);
      z.w = fmaf(nz.w, expf(0.5f * v.w), m.w);
      ((float4*)outZ)[oi] = z;
      ((float4*)outM)[oi] = m;
      ((float4*)outLv)[oi] = v;
    }
  }
}

// ---------- launch ----------

extern "C" void kernel_launch(void* const* d_in, const int* in_sizes, int n_in,
                              void* d_out, int out_size, void* d_ws, size_t ws_size,
                              hipStream_t stream) {
  const float* x     = (const float*)d_in[0];
  const int*   edge  = (const int*)d_in[1];
  const float* W1    = (const float*)d_in[2];
  const float* b1    = (const float*)d_in[3];
  const float* Wm    = (const float*)d_in[4];
  const float* bm    = (const float*)d_in[5];
  const float* Wv    = (const float*)d_in[6];
  const float* bv    = (const float*)d_in[7];
  const float* noise = (const float*)d_in[8];
  int n = in_sizes[0] / 128;
  int e = in_sizes[1] / 2;
  const int* src = edge;
  const int* dst = edge + e;
  int nc = (n + CMASK) >> CSHIFT;   // 49 coarse buckets of 2048 nodes

  // workspace layout (int units, 16B-aligned segments)
  int* ccnt = (int*)d_ws;                          // NCMAX*16 (1 per 64B line)
  int* ccur = ccnt + NCMAX * 16;                   // NCMAX*16
  int* coff = ccur + NCMAX * 16;                   // NCMAX+1 (+pad)
  int* off  = coff + (NCMAX + 4);                  // n+1 (+pad)
  float* dinv = (float*)(off + ((n + 4) & ~3));    // n
  unsigned int* packed = (unsigned int*)(dinv + ((n + 3) & ~3)); // e
  int* csr  = (int*)(packed + ((e + 3) & ~3));     // e
  unsigned int* h1b = (unsigned int*)(csr + ((e + 3) & ~3)); // n*32 (bf16 h1')
  unsigned int* hb  = h1b + (size_t)n * 32;                  // n*32 (bf16 h')
  unsigned int* aggb = hb + (size_t)n * 32;                  // n*32 (bf16 agg2)

  float* outZ  = (float*)d_out;
  float* outM  = outZ + (size_t)n * 32;
  float* outLv = outM + (size_t)n * 32;

  int ntiles = (e + TILE - 1) / TILE;

  zero_kernel<<<(NCMAX * 16 + 255) / 256, 256, 0, stream>>>(ccnt, NCMAX * 16);
  coarse_hist_kernel<<<256, 256, 0, stream>>>(dst, ccnt, e);
  coarse_scan_kernel<<<1, 64, 0, stream>>>(ccnt, coff, ccur, off, nc, n, e);
  coarse_partition_kernel<<<ntiles, 256, 0, stream>>>(src, dst, ccur, packed, e);
  csr_fine_kernel<<<nc, 512, 0, stream>>>(packed, coff, off, dinv, csr, n);
  gemm1_kernel<<<(n + 63) / 64, 256, 0, stream>>>(x, W1, dinv, h1b, n);
  agg_kernel<1><<<(n + 3) / 4, 256, 0, stream>>>((const uint4*)h1b, off, csr, dinv, b1, hb, n);
  agg_kernel<0><<<(n + 3) / 4, 256, 0, stream>>>((const uint4*)hb, off, csr, dinv, b1, aggb, n);
  final_kernel<<<(n + 63) / 64, 256, 0, stream>>>(aggb, Wm, bm, Wv, bv, noise, outZ, outM, outLv, n);
}